// Round 10
// baseline (1758.679 us; speedup 1.0000x reference)
//
#include <hip/hip_runtime.h>
#include <stdint.h>

// Model dims
#define D_   1024
#define T_   512
#define B_   8
#define V_   8
#define I_   1032
#define KP_  1088
#define TDK  3072
#define NGRU 32
#define NHELP 224

typedef __attribute__((ext_vector_type(8))) short bf16x8;
typedef __attribute__((ext_vector_type(4))) float f32x4;

__device__ __forceinline__ ushort f2bf(float f){
  union{ unsigned u; float f; } c; c.f = f;
  unsigned u = c.u;
  return (ushort)((u + 0x7FFFu + ((u>>16)&1u)) >> 16);   // RNE
}
__device__ __forceinline__ float bf2f(ushort h){
  union{ unsigned u; float f; } c; c.u = ((unsigned)h) << 16; return c.f;
}
__device__ __forceinline__ float sigmoidf_(float x){ return 1.f/(1.f+__expf(-x)); }

#define WAITV(N) do{ asm volatile("s_waitcnt vmcnt(" #N ")" ::: "memory"); __builtin_amdgcn_sched_barrier(0); }while(0)

__device__ __forceinline__ void gload_lds16(const void* g, void* l){
  __builtin_amdgcn_global_load_lds((const __attribute__((address_space(1))) void*)g,
                                   (__attribute__((address_space(3))) void*)l, 16, 0, 0);
}

// ---------------- prep: x*mask -> f32 + bf16 ----------------
__global__ __launch_bounds__(256) void k_prep(const float* __restrict__ x, const float* __restrict__ mask,
                                              float* __restrict__ xm, ushort* __restrict__ xmb){
  int i = blockIdx.x*256 + threadIdx.x;
  float4 v = ((const float4*)x)[i];
  float mk = mask[i >> 8];
  v.x*=mk; v.y*=mk; v.z*=mk; v.w*=mk;
  ((float4*)xm)[i] = v;
  ushort4 h; h.x=f2bf(v.x); h.y=f2bf(v.y); h.z=f2bf(v.z); h.w=f2bf(v.w);
  ((ushort4*)xmb)[i] = h;
}

// init h slot 0: value bf16(0), tag 1
__global__ __launch_bounds__(256) void k_hinit(unsigned* __restrict__ hw){
  hw[blockIdx.x*256 + threadIdx.x] = 1u;
}

__global__ __launch_bounds__(256) void k_cvt(const float* __restrict__ in, ushort* __restrict__ out, int n4){
  int i = blockIdx.x*256 + threadIdx.x;
  if (i < n4){
    float4 v = ((const float4*)in)[i];
    ushort4 h; h.x=f2bf(v.x); h.y=f2bf(v.y); h.z=f2bf(v.z); h.w=f2bf(v.w);
    ((ushort4*)out)[i] = h;
  }
}

// ---------------- bf16 MFMA GEMM (m97 structure) ----------------
struct EpiArgs {
  float* outf; ushort* outh;
  const float* bias; const float* wvp; const float* obias;
  int ldc;
};

template<int EPI, bool INIT>
__global__ __launch_bounds__(256) void k_gemm(const ushort* __restrict__ A, const ushort* __restrict__ Bm,
                                              int lda, int ldb, int K, EpiArgs e)
{
  __shared__ ushort As[128*64];
  __shared__ ushort Bs[128*64];
  const int tid = threadIdx.x;
  const int w = tid >> 6, l = tid & 63;
  const int wr = w >> 1, wc = w & 1;
  f32x4 acc[4][4] = {};
  const size_t arow = (size_t)(blockIdx.x*128);
  const size_t brow = (size_t)(blockIdx.y*128);
  const int lr = l >> 3, lcol = (l & 7) << 3;

  for (int k0 = 0; k0 < K; k0 += 64){
    __syncthreads();
    #pragma unroll
    for (int g = 0; g < 4; ++g){
      const int chunk = (g<<2) + w;
      const int row = (chunk<<3) + lr;
      gload_lds16(A + (arow + row)*lda + k0 + lcol, &As[chunk<<9]);
      gload_lds16(Bm + (brow + row)*ldb + k0 + lcol, &Bs[chunk<<9]);
    }
    __syncthreads();
    #pragma unroll
    for (int kk = 0; kk < 2; ++kk){
      bf16x8 af[4], bfr[4];
      #pragma unroll
      for (int m=0;m<4;++m) af[m]  = *(const bf16x8*)&As[(wr*64 + m*16 + (l&15))*64 + kk*32 + ((l>>4)<<3)];
      #pragma unroll
      for (int n=0;n<4;++n) bfr[n] = *(const bf16x8*)&Bs[(wc*64 + n*16 + (l&15))*64 + kk*32 + ((l>>4)<<3)];
      #pragma unroll
      for (int m=0;m<4;++m)
        #pragma unroll
        for (int n=0;n<4;++n)
          acc[m][n] = __builtin_amdgcn_mfma_f32_16x16x32_bf16(af[m], bfr[n], acc[m][n], 0, 0, 0);
    }
  }
  const int row0 = blockIdx.x*128 + wr*64 + ((l>>4)<<2);
  const int col0 = blockIdx.y*128 + wc*64 + (l&15);
  #pragma unroll
  for (int m=0;m<4;++m){
    #pragma unroll
    for (int n=0;n<4;++n){
      f32x4 a = acc[m][n];
      int col = col0 + n*16;
      #pragma unroll
      for (int q=0;q<4;++q){
        int row = row0 + m*16 + q;
        float val = a[q];
        if constexpr (EPI==1){
          float xg = val + e.bias[col];
          float g = 0.5f*xg*(1.0f + erff(xg*0.70710678118f));
          e.outh[(size_t)row*e.ldc + col] = f2bf(g * e.wvp[(row>>9)*V_ + (col>>10)]);
        } else {
          size_t idx = (size_t)row*e.ldc + col;
          float prev = INIT ? e.obias[((row>>9)<<10) + col] : e.outf[idx];
          e.outf[idx] = prev + val;
        }
      }
    }
  }
}

// ================= MEGA KERNEL: 32-WG GRU (R6-validated datapath, R7 exchange) =================
__global__ __launch_bounds__(256, 1) void k_mega(
    const float* __restrict__ whh, const float* __restrict__ bhh,
    const ushort* __restrict__ xmb, const ushort* __restrict__ wihb,
    const float* __restrict__ ebih, float* __restrict__ gx,
    unsigned* __restrict__ hw, const float* __restrict__ xm,
    const float* __restrict__ ttW, const float* __restrict__ ttb,
    const float* __restrict__ polW, const float* __restrict__ polb,
    ushort* __restrict__ tf, float* __restrict__ ttpol,
    const float* __restrict__ opW1, ushort* __restrict__ w1b,
    const float* __restrict__ opW2, ushort* __restrict__ w2t,
    float* __restrict__ hsum, float* __restrict__ xsum,
    int* __restrict__ done, int* __restrict__ wm)
{
  __shared__ char smem[41600];
  const int tid = threadIdx.x;
  const int w = tid >> 6, l = tid & 63;

  if (blockIdx.x < NGRU){
    // ---------------- GRU path: WG owns dims [32*slot, 32*slot+32) ----------------
    const int slot = blockIdx.x;
    ushort (*Hld)[264] = (ushort (*)[264])smem;         // [4*8][264]
    float* Red = (float*)(smem + 16896);                // [2][4][6][128]
    const int ar = l & 15, kg = (l >> 4) << 3;

    // W_hh fragments: 6 B-frags (96 rows) x 8 k-slots, K-quarter per wave -> 192 VGPR
    bf16x8 Bf[6][8];
    #pragma unroll
    for (int f = 0; f < 6; ++f){
      const int rr = f*16 + (l & 15);
      const int g = rr >> 5, i = rr & 31;
      #pragma unroll
      for (int ks = 0; ks < 8; ++ks){
        const float* src = whh + ((size_t)((g<<10) + (slot<<5) + i))*1024 + (w<<8) + (ks<<5) + kg;
        float4 u0 = *(const float4*)src;
        float4 u1 = *(const float4*)(src + 4);
        bf16x8 fr;
        fr[0]=(short)f2bf(u0.x); fr[1]=(short)f2bf(u0.y); fr[2]=(short)f2bf(u0.z); fr[3]=(short)f2bf(u0.w);
        fr[4]=(short)f2bf(u1.x); fr[5]=(short)f2bf(u1.y); fr[6]=(short)f2bf(u1.z); fr[7]=(short)f2bf(u1.w);
        Bf[f][ks] = fr;
      }
    }
    const int gb = tid >> 5, gi = tid & 31;             // batch, dim-in-32
    const int dg = (slot << 5) + gi;
    const int n_ = gi & 15, fb = gi >> 4;
    const int idxc = (((gb>>2)<<4) + n_)*4 + (gb & 3);
    const float bhr = bhh[dg], bhz = bhh[1024 + dg], bhn = bhh[2048 + dg];
    float hp = 0.f, hacc = 0.f;
    float xr, xz, xn, nxr, nxz, nxn;
    __syncthreads();

    // gate gx block 0
    {
      const int* dp = done + l*3;
      int f0, f1, f2;
      while (true){
        asm volatile("global_load_dword %0, %1, off sc0 sc1" : "=v"(f0) : "v"(dp)   : "memory");
        asm volatile("global_load_dword %0, %1, off sc0 sc1" : "=v"(f1) : "v"(dp+1) : "memory");
        asm volatile("global_load_dword %0, %1, off sc0 sc1" : "=v"(f2) : "v"(dp+2) : "memory");
        WAITV(0);
        if (__all((f0 & f1 & f2) == 1)) break;
        __builtin_amdgcn_s_sleep(4);
      }
    }
    __syncthreads();
    // prologue gx(0) — every thread owns (batch gb, dim dg)
    {
      const float* g0 = gx + ((size_t)(gb*512))*TDK + dg;
      asm volatile("global_load_dword %0, %1, off sc0 sc1" : "=v"(xr) : "v"(g0)        : "memory");
      asm volatile("global_load_dword %0, %1, off sc0 sc1" : "=v"(xz) : "v"(g0 + 1024) : "memory");
      asm volatile("global_load_dword %0, %1, off sc0 sc1" : "=v"(xn) : "v"(g0 + 2048) : "memory");
    }
    WAITV(0);

    for (int t = 0; t < 512; ++t){
      if ((t & 127) == 0 && t){
        const int tq = t >> 7;
        const int* dp = done + tq*192 + l*3;
        int f0, f1, f2;
        while (true){
          asm volatile("global_load_dword %0, %1, off sc0 sc1" : "=v"(f0) : "v"(dp)   : "memory");
          asm volatile("global_load_dword %0, %1, off sc0 sc1" : "=v"(f1) : "v"(dp+1) : "memory");
          asm volatile("global_load_dword %0, %1, off sc0 sc1" : "=v"(f2) : "v"(dp+2) : "memory");
          WAITV(0);
          if (__all((f0 & f1 & f2) == 1)) break;
          __builtin_amdgcn_s_sleep(4);
        }
        __syncthreads();
        {
          const float* g0 = gx + ((size_t)(gb*512 + t))*TDK + dg;
          asm volatile("global_load_dword %0, %1, off sc0 sc1" : "=v"(xr) : "v"(g0)        : "memory");
          asm volatile("global_load_dword %0, %1, off sc0 sc1" : "=v"(xz) : "v"(g0 + 1024) : "memory");
          asm volatile("global_load_dword %0, %1, off sc0 sc1" : "=v"(xn) : "v"(g0 + 2048) : "memory");
        }
        WAITV(0);
      }
      // poll slot t (polls first, then gx(t+1); counted wait keeps ONLY the 3 gx outstanding)
      uint4 rw[8];
      unsigned ok = 0;
      const unsigned tagv = (unsigned)(t + 1);
      const unsigned* qb = hw + ((size_t)t << 13) + (w << 8) + (l << 2);
      #pragma unroll
      for (int j = 0; j < 8; ++j)
        asm volatile("global_load_dwordx4 %0, %1, off sc0 sc1" : "=v"(rw[j]) : "v"(qb + (j << 10)) : "memory");
      const bool gxi = (((t+1) & 127) != 0) && (t+1 < 512);
      if (gxi){
        const float* g0 = gx + ((size_t)(gb*512 + t + 1))*TDK + dg;
        asm volatile("global_load_dword %0, %1, off sc0 sc1" : "=v"(nxr) : "v"(g0)        : "memory");
        asm volatile("global_load_dword %0, %1, off sc0 sc1" : "=v"(nxz) : "v"(g0 + 1024) : "memory");
        asm volatile("global_load_dword %0, %1, off sc0 sc1" : "=v"(nxn) : "v"(g0 + 2048) : "memory");
      }
      // queue per lane = [h-store(<=1), 8 polls, 3 gx] -> WAITV(3) drains store+polls
      if (gxi) { WAITV(3); } else { WAITV(0); }
      #pragma unroll
      for (int j = 0; j < 8; ++j){
        unsigned m = (rw[j].x ^ tagv) | (rw[j].y ^ tagv) | (rw[j].z ^ tagv) | (rw[j].w ^ tagv);
        if ((m & 0xFFFFu) == 0u) ok |= (1u << j);
      }
      while (!__all(ok == 0xFFu)){
        #pragma unroll
        for (int j = 0; j < 8; ++j){
          if (!(ok & (1u << j)))
            asm volatile("global_load_dwordx4 %0, %1, off sc0 sc1" : "=v"(rw[j]) : "v"(qb + (j << 10)) : "memory");
        }
        WAITV(0);
        #pragma unroll
        for (int j = 0; j < 8; ++j){
          if (!(ok & (1u << j))){
            unsigned m = (rw[j].x ^ tagv) | (rw[j].y ^ tagv) | (rw[j].z ^ tagv) | (rw[j].w ^ tagv);
            if ((m & 0xFFFFu) == 0u) ok |= (1u << j);
          }
        }
      }
      // strip tags -> wave-private LDS
      #pragma unroll
      for (int j = 0; j < 8; ++j){
        unsigned d0 = __builtin_amdgcn_perm(rw[j].y, rw[j].x, 0x07060302u);
        unsigned d1 = __builtin_amdgcn_perm(rw[j].w, rw[j].z, 0x07060302u);
        union { unsigned u[2]; unsigned long long ull; } cv; cv.u[0]=d0; cv.u[1]=d1;
        *(unsigned long long*)&Hld[w*8 + j][l<<2] = cv.ull;
      }
      // 48 MFMAs: 6 B-frags x 8 k-slots
      f32x4 ac[6] = {};
      #pragma unroll
      for (int ks = 0; ks < 8; ++ks){
        bf16x8 af = *(const bf16x8*)&Hld[w*8 + (ar & 7)][(ks << 5) + kg];
        #pragma unroll
        for (int f = 0; f < 6; ++f)
          ac[f] = __builtin_amdgcn_mfma_f32_16x16x32_bf16(af, Bf[f][ks], ac[f], 0, 0, 0);
      }
      const int cur = t & 1;
      if (l < 32){
        float* Rb = Red + cur*3072 + w*768;
        #pragma unroll
        for (int f = 0; f < 6; ++f) *(f32x4*)(Rb + f*128 + l*4) = ac[f];
      }
      __syncthreads();
      {
        const float* R = Red + cur*3072;
        float ghr = 0.f, ghz = 0.f, ghn = 0.f;
        #pragma unroll
        for (int ww = 0; ww < 4; ++ww){
          const float* Rw = R + ww*768;
          ghr += Rw[(0*2 + fb)*128 + idxc];
          ghz += Rw[(1*2 + fb)*128 + idxc];
          ghn += Rw[(2*2 + fb)*128 + idxc];
        }
        float r  = sigmoidf_(xr + ghr + bhr);
        float z  = sigmoidf_(xz + ghz + bhz);
        float nn = tanhf(xn + r*(ghn + bhn));
        hp = (1.f - z)*nn + z*hp;
        hacc += hp;
        unsigned word = (((unsigned)f2bf(hp)) << 16) | (unsigned)(t + 2);
        unsigned* hdst = hw + ((size_t)(t+1) << 13) + (gb << 10) + dg;
        asm volatile("global_store_dword %0, %1, off sc0 sc1" :: "v"(hdst), "v"(word) : "memory");
      }
      if (slot == 0 && tid == 0){
        asm volatile("global_store_dword %0, %1, off sc0 sc1" :: "v"(wm), "v"(t) : "memory");
      }
      if (gxi){ xr = nxr; xz = nxz; xn = nxn; }
    }
    hsum[(gb << 10) + dg] = hacc;
    return;
  }

  // ---------------- helper path ----------------
  const int hid = blockIdx.x - NGRU;            // 0..223
  ushort* As = (ushort*)smem;
  ushort* Bs = As + 8192;

  // phase 1: gx GEMM tiles (first 192 helpers), t-priority order
  if (hid < 192){
    const int bb = hid / 24, ni = hid % 24;
    const int wr_ = w >> 1, wc_ = w & 1;
    const int lr = l >> 3, lcol = (l & 7) << 3;
    for (int wv = 0; wv < 4; ++wv){
      const int mi = bb*4 + wv;
      f32x4 acc[4][4] = {};
      for (int k0 = 0; k0 < 1024; k0 += 64){
        __syncthreads();
        #pragma unroll
        for (int g = 0; g < 4; ++g){
          const int chunk = (g<<2) + w;
          const int row = (chunk<<3) + lr;
          gload_lds16(xmb + (size_t)(mi*128 + row)*1024 + k0 + lcol, &As[chunk<<9]);
          gload_lds16(wihb + (size_t)(ni*128 + row)*1024 + k0 + lcol, &Bs[chunk<<9]);
        }
        __syncthreads();
        #pragma unroll
        for (int kk = 0; kk < 2; ++kk){
          bf16x8 af[4], bfr[4];
          #pragma unroll
          for (int m=0;m<4;++m) af[m]  = *(const bf16x8*)&As[(wr_*64 + m*16 + (l&15))*64 + kk*32 + ((l>>4)<<3)];
          #pragma unroll
          for (int n=0;n<4;++n) bfr[n] = *(const bf16x8*)&Bs[(wc_*64 + n*16 + (l&15))*64 + kk*32 + ((l>>4)<<3)];
          #pragma unroll
          for (int m=0;m<4;++m)
            #pragma unroll
            for (int n=0;n<4;++n)
              acc[m][n] = __builtin_amdgcn_mfma_f32_16x16x32_bf16(af[m], bfr[n], acc[m][n], 0, 0, 0);
        }
      }
      const int row0 = mi*128 + wr_*64 + ((l>>4)<<2);
      const int col0 = ni*128 + wc_*64 + (l&15);
      #pragma unroll
      for (int m=0;m<4;++m){
        #pragma unroll
        for (int n=0;n<4;++n){
          f32x4 a = acc[m][n];
          int col = col0 + n*16;
          float bi = ebih[col];
          #pragma unroll
          for (int q=0;q<4;++q){
            int row = row0 + m*16 + q;
            float val = a[q] + bi;
            float* p = gx + (size_t)row*TDK + col;
            asm volatile("global_store_dword %0, %1, off sc0 sc1" :: "v"(p), "v"(val) : "memory");
          }
        }
      }
      WAITV(0);
      __syncthreads();
      if (tid == 0){
        int one = 1;
        const int* fp = done + wv*192 + hid;
        asm volatile("global_store_dword %0, %1, off sc0 sc1" :: "v"(fp), "v"(one) : "memory");
      }
      __syncthreads();
    }
  }
  // phase 2: weight conversions
  for (int row = hid; row < 8192; row += NHELP){
    const float* src = opW1 + (size_t)row*I_;
    ushort* dst = w1b + (size_t)row*KP_;
    for (int cc = tid; cc < KP_; cc += 256){
      float v = (cc < I_) ? src[cc] : 0.f;
      dst[cc] = f2bf(v);
    }
  }
  for (int blk = hid; blk < 8192; blk += NHELP){
    const int v = blk >> 10, d = blk & 1023;
    const float4* src = (const float4*)(opW2 + ((size_t)(v*1024 + d))*1024);
    ushort* dst = w2t + (size_t)d*8192 + v*1024;
    float4 u = src[tid];
    ushort4 h; h.x=f2bf(u.x); h.y=f2bf(u.y); h.z=f2bf(u.z); h.w=f2bf(u.w);
    ((ushort4*)dst)[tid] = h;
  }
  // phase 3: xsum
  if (hid < 32){
    const int o = hid*256 + tid;
    const int b = o >> 10, d = o & 1023;
    float s = 0.f;
    for (int t = 0; t < 512; ++t) s += xm[((size_t)(b*512 + t) << 10) + d];
    xsum[o] = s;
  }
  // phase 4: tokfeat per token, gated by watermark + tag-check
  {
    float* xe = (float*)smem;
    for (int idx = hid; idx < 4096; idx += NHELP){
      const int t = idx >> 3, b = idx & 7;
      const int tok = b*512 + t;
      const int need = (t+1 < 511) ? (t+1) : 511;
      if (tid == 0){
        int wmv;
        while (true){
          asm volatile("global_load_dword %0, %1, off sc0 sc1" : "=v"(wmv) : "v"(wm) : "memory");
          asm volatile("s_waitcnt vmcnt(0)" ::: "memory");
          if (wmv >= need) break;
          __builtin_amdgcn_s_sleep(64);
        }
      }
      __syncthreads();
      const unsigned tagv = (unsigned)(t + 2);
      const unsigned* src = hw + ((size_t)(t+1) << 13) + (b << 10) + (tid << 2);
      uint4 hv;
      while (true){
        asm volatile("global_load_dwordx4 %0, %1, off sc0 sc1" : "=v"(hv) : "v"(src) : "memory");
        WAITV(0);
        unsigned m = (hv.x ^ tagv) | (hv.y ^ tagv) | (hv.z ^ tagv) | (hv.w ^ tagv);
        if (__syncthreads_and((int)((m & 0xFFFFu) == 0u))) break;
        __builtin_amdgcn_s_sleep(16);
      }
      float4 xv = ((const float4*)(xm + (size_t)tok*1024))[tid];
      float4 ev;
      ev.x = bf2f((ushort)(hv.x >> 16)) + xv.x;
      ev.y = bf2f((ushort)(hv.y >> 16)) + xv.y;
      ev.z = bf2f((ushort)(hv.z >> 16)) + xv.z;
      ev.w = bf2f((ushort)(hv.w >> 16)) + xv.w;
      *(float4*)&xe[tid*4] = ev;
      ushort4 eb; eb.x=f2bf(ev.x); eb.y=f2bf(ev.y); eb.z=f2bf(ev.z); eb.w=f2bf(ev.w);
      *(ushort4*)&tf[(size_t)tok*KP_ + tid*4] = eb;
      __syncthreads();
      const int j = tid >> 5, ln = tid & 31;
      const float* Wr = (j < 6) ? (ttW + j*1024) : (polW + (j-6)*1024);
      float acc = 0.f;
      for (int k = ln; k < 1024; k += 32) acc += xe[k]*Wr[k];
      #pragma unroll
      for (int m=16; m>=1; m>>=1) acc += __shfl_xor(acc, m, 32);
      if (ln == 0){
        float val = acc + ((j<6)? ttb[j] : polb[j-6]);
        ttpol[(size_t)tok*8 + j] = val;
        tf[(size_t)tok*KP_ + 1024 + j] = f2bf(val);
      }
      if (tid < 56) tf[(size_t)tok*KP_ + 1032 + tid] = 0;
      __syncthreads();
    }
  }
}

__global__ __launch_bounds__(64) void k_csum(const float* __restrict__ ttpol, float* __restrict__ csum){
  const int b = threadIdx.x >> 3, j = threadIdx.x & 7;
  float s = 0.f;
  for (int t=0; t<512; ++t) s += ttpol[((size_t)(b*512+t)<<3) + j];
  csum[threadIdx.x] = s * (1.f/512.f);
}

__global__ __launch_bounds__(256) void k_ctx(const float* __restrict__ hsum, const float* __restrict__ xsum,
                                             const float* __restrict__ csum,
                                             const float* __restrict__ c2hW, const float* __restrict__ c2hb,
                                             float* __restrict__ pgh0){
  const int i = blockIdx.x*256 + threadIdx.x;
  const int b = i >> 10, d = i & 1023;
  const float* wr = c2hW + (size_t)d*I_;
  const float* hs = hsum + (b<<10);
  const float* xs = xsum + (b<<10);
  float s = 0.f;
  for (int k=0; k<1024; ++k) s += (hs[k]+xs[k])*wr[k];
  float acc = c2hb[d] + s*(1.f/512.f);
  #pragma unroll
  for (int k=0; k<8; ++k) acc += csum[b*8+k]*wr[1024+k];
  pgh0[i] = acc;
}

__global__ __launch_bounds__(256) void k_pg(const float* __restrict__ whh, const float* __restrict__ bih,
                                            const float* __restrict__ bhh, const float* __restrict__ hin,
                                            float* __restrict__ hout){
  __shared__ float sh[8][1024];
  const int tid = threadIdx.x;
  for (int f = tid; f < 2048; f += 256) ((float4*)&sh[0][0])[f] = ((const float4*)hin)[f];
  __syncthreads();
  const int d = blockIdx.x*8 + (tid>>5), ln = tid & 31;
  const float* wr = whh + (size_t)d*1024;
  const float* wz = whh + (size_t)(1024+d)*1024;
  const float* wn = whh + (size_t)(2048+d)*1024;
  float ar[8]={0,0,0,0,0,0,0,0}, az[8]={0,0,0,0,0,0,0,0}, an[8]={0,0,0,0,0,0,0,0};
  for (int k = ln; k < 1024; k += 32){
    float r_=wr[k], z_=wz[k], n_=wn[k];
    #pragma unroll
    for (int b=0;b<8;++b){ float h = sh[b][k]; ar[b]+=h*r_; az[b]+=h*z_; an[b]+=h*n_; }
  }
  #pragma unroll
  for (int m=16; m>=1; m>>=1){
    #pragma unroll
    for (int b=0;b<8;++b){ ar[b]+=__shfl_xor(ar[b],m,32); az[b]+=__shfl_xor(az[b],m,32); an[b]+=__shfl_xor(an[b],m,32); }
  }
  if (ln == 0){
    float xr=bih[d], xz=bih[1024+d], xn=bih[2048+d];
    float br=bhh[d], bz=bhh[1024+d], bn=bhh[2048+d];
    #pragma unroll
    for (int b=0;b<8;++b){
      float r = sigmoidf_(xr + ar[b] + br);
      float z = sigmoidf_(xz + az[b] + bz);
      float nn = tanhf(xn + r*(an[b] + bn));
      hout[(b<<10)+d] = (1.f - z)*nn + z*sh[b][d];
    }
  }
}

__global__ __launch_bounds__(256) void k_wlogits(const float* __restrict__ pgh, const float* __restrict__ prjW,
                                                 const float* __restrict__ prjb, float* __restrict__ plog,
                                                 float* __restrict__ wv){
  __shared__ float lg[256];
  __shared__ float sm[256];
  const int tid = threadIdx.x;
  const int b = tid>>5, li = (tid>>3)&3, v = tid&7;
  const float* h = pgh + (size_t)(li+1)*8192 + (b<<10);
  const float* pw = prjW + (v<<10);
  float acc = prjb[v];
  for (int k=0;k<1024;++k) acc += h[k]*pw[k];
  lg[tid] = acc;
  plog[tid] = acc;
  __syncthreads();
  if (tid < 32){
    const int bb = tid>>2, ll = tid&3;
    const float* row = &lg[bb*32 + ll*8];
    float mx = row[0];
    #pragma unroll
    for (int u=1;u<8;++u) mx = fmaxf(mx, row[u]);
    float e[8], s=0.f;
    #pragma unroll
    for (int u=0;u<8;++u){ e[u]=__expf(row[u]-mx); s+=e[u]; }
    #pragma unroll
    for (int u=0;u<8;++u) sm[(bb*4+ll)*8+u] = e[u]/s;
  }
  __syncthreads();
  if (tid < 64){
    const int bb = tid>>3, u = tid&7;
    float s = sm[(bb*4+0)*8+u] + sm[(bb*4+1)*8+u] + sm[(bb*4+2)*8+u] + sm[(bb*4+3)*8+u];
    wv[bb*8+u] = 0.25f*s;
  }
}

__global__ __launch_bounds__(256) void k_obias(const float* __restrict__ wv, const float* __restrict__ opb2,
                                               float* __restrict__ obias){
  const int i = blockIdx.x*256 + threadIdx.x;
  const int b = i>>10, d = i&1023;
  float s = 0.f;
  #pragma unroll
  for (int v=0; v<8; ++v) s += wv[b*8+v]*opb2[(v<<10)+d];
  obias[i] = s;
}

__global__ __launch_bounds__(128) void k_pool2(const float* __restrict__ outb, float* __restrict__ pooled2){
  const int b = blockIdx.x >> 3;
  const int col = ((blockIdx.x & 7) << 7) + threadIdx.x;
  float mx = -3.4e38f, sm = 0.f;
  for (int t=0; t<512; ++t){
    float v = outb[((size_t)(b*512+t)<<10) + col];
    mx = fmaxf(mx, v); sm += v;
  }
  pooled2[((size_t)b<<11) + col] = mx;
  pooled2[((size_t)b<<11) + 1024 + col] = sm*(1.f/512.f);
}

__global__ __launch_bounds__(256) void k_z(const float* __restrict__ pooled2, const float* __restrict__ outW,
                                           const float* __restrict__ outBias, float* __restrict__ dout){
  __shared__ float p2[2048];
  const int o = blockIdx.x << 3;
  const int b = o >> 10, dbase = o & 1023;
  for (int f = threadIdx.x; f < 512; f += 256)
    ((float4*)p2)[f] = ((const float4*)(pooled2 + ((size_t)b<<11)))[f];
  __syncthreads();
  const int g = threadIdx.x >> 5, ln = threadIdx.x & 31;
  const int d = dbase + g;
  const float* wr = outW + ((size_t)d << 11);
  float acc = 0.f;
  for (int k = ln; k < 2048; k += 32) acc += p2[k]*wr[k];
  #pragma unroll
  for (int m=16; m>=1; m>>=1) acc += __shfl_xor(acc, m, 32);
  if (ln == 0) dout[(b<<10) + d] = acc + outBias[d];
}

__global__ __launch_bounds__(64) void k_losses(const float* __restrict__ p2g, const float* __restrict__ plog,
                                               float* __restrict__ dout){
  __shared__ float p2n[8], sq[8], pn[8];
  const int l = threadIdx.x;
  { const int b=l>>3, p=l&7; float s=0.f;
    const float* row = p2g + ((size_t)b<<11) + (p<<8);
    for (int k=0;k<256;++k){ float v=row[k]; s += v*v; }
    s += __shfl_xor(s,4,8); s += __shfl_xor(s,2,8); s += __shfl_xor(s,1,8);
    if (p==0) p2n[b] = fmaxf(sqrtf(s), 1e-12f);
  }
  if (l < 8){
    float s=0.f;
    #pragma unroll
    for (int k=0;k<32;++k){ float v=plog[l*32+k]; s+=v*v; }
    sq[l]=s; pn[l]=fmaxf(sqrtf(s),1e-12f);
  }
  __syncthreads();
  const int i=l>>3, j=l&7;
  const float* ri = p2g + ((size_t)i<<11);
  const float* rj = p2g + ((size_t)j<<11);
  float dot=0.f; for (int k=0;k<2048;++k) dot += ri[k]*rj[k];
  float sim = dot/(p2n[i]*p2n[j]);
  float pd=0.f;
  #pragma unroll
  for (int k=0;k<32;++k) pd += plog[i*32+k]*plog[j*32+k];
  float d2 = fmaxf(sq[i]+sq[j]-2.f*pd, 0.f);
  float dist = (d2>0.f)? sqrtf(d2) : 0.f;
  float psim = pd/(pn[i]*pn[j]);
  float pos = (sim>0.7f)?1.f:0.f, neg = (sim<0.7f)?1.f:0.f;
  float rs = sim*dist, ps=(1.f-psim)*pos, ns=fmaxf(psim-0.5f,0.f)*neg, pc=pos, nc=neg;
  #pragma unroll
  for (int m=32; m>=1; m>>=1){
    rs+=__shfl_xor(rs,m); ps+=__shfl_xor(ps,m); ns+=__shfl_xor(ns,m);
    pc+=__shfl_xor(pc,m); nc+=__shfl_xor(nc,m);
  }
  if (l==0){ dout[8192]=rs*(1.f/64.f); dout[8193]=(ps+ns)/(pc+nc+1e-6f); }
}

// ============================ host ============================
extern "C" void kernel_launch(void* const* d_in, const int* in_sizes, int n_in,
                              void* d_out, int out_size, void* d_ws, size_t ws_size,
                              hipStream_t stream) {
  (void)in_sizes; (void)n_in; (void)out_size; (void)ws_size;
  const float* x     = (const float*)d_in[0];
  const float* amask = (const float*)d_in[1];
  const float* eWih  = (const float*)d_in[2];
  const float* eWhh  = (const float*)d_in[3];
  const float* ebih  = (const float*)d_in[4];
  const float* ebhh  = (const float*)d_in[5];
  const float* ttW   = (const float*)d_in[6];
  const float* ttb   = (const float*)d_in[7];
  const float* polW  = (const float*)d_in[8];
  const float* polb  = (const float*)d_in[9];
  const float* c2hW  = (const float*)d_in[10];
  const float* c2hb  = (const float*)d_in[11];
  const float* pgWhh = (const float*)d_in[13];
  const float* pgbih = (const float*)d_in[14];
  const float* pgbhh = (const float*)d_in[15];
  const float* prjW  = (const float*)d_in[16];
  const float* prjb  = (const float*)d_in[17];
  const float* opW1  = (const float*)d_in[18];
  const float* opb1  = (const float*)d_in[19];
  const float* opW2  = (const float*)d_in[20];
  const float* opb2  = (const float*)d_in[21];
  const float* outW  = (const float*)d_in[22];
  const float* outB  = (const float*)d_in[23];
  float* dout = (float*)d_out;

  char* ws = (char*)d_ws;
  size_t off = 0;
  auto alloc = [&](size_t bytes)->void*{ void* p = ws + off; off += (bytes + 255) & ~(size_t)255; return p; };
  char*     R       = (char*)   alloc(64ULL*1024*1024);   // xm(16M)+gx(48M) -> reused as h1g(64M)
  float*    xm      = (float*)  R;
  float*    gx      = (float*) (R + 16ULL*1024*1024);
  ushort*   h1g     = (ushort*) R;
  ushort*   xmb     = (ushort*)  alloc(4096ULL*1024*2);
  ushort*   wihb    = (ushort*)  alloc(3072ULL*1024*2);
  unsigned* hw      = (unsigned*)alloc(513ULL*8192*4);
  float*    ttpol   = (float*)   alloc(4096ULL*8*4);
  ushort*   tf      = (ushort*)  alloc(4096ULL*KP_*2);
  ushort*   w1b     = (ushort*)  alloc(8ULL*1024*KP_*2);
  ushort*   w2t     = (ushort*)  alloc(1024ULL*8192*2);
  float*    outbuf  = (float*)   alloc(4096ULL*1024*4);
  float*    hsum    = (float*)   alloc(8192*4);
  float*    xsum    = (float*)   alloc(8192*4);
  float*    csum    = (float*)   alloc(64*4);
  float*    pgh     = (float*)   alloc(5ULL*8192*4);
  float*    plog    = (float*)   alloc(256*4);
  float*    wv      = (float*)   alloc(64*4);
  float*    obias   = (float*)   alloc(8192*4);
  float*    pooled2 = (float*)   alloc(16384*4);
  int*      ctrl    = (int*)     alloc(4096);
  int*      done    = ctrl;                     // [4*192]
  int*      wm      = ctrl + 896;               // separate line

  // control init + exchange-buffer init
  hipMemsetAsync(done, 0, 4*192*4, stream);
  hipMemsetAsync(wm, 0xFF, 4, stream);          // wm = -1
  k_hinit<<<32, 256, 0, stream>>>(hw);          // slot 0: value 0, tag 1
  k_prep<<<4096, 256, 0, stream>>>(x, amask, xm, xmb);
  k_cvt<<<3072, 256, 0, stream>>>(eWih, wihb, 3072*1024/4);

  // MEGA: recurrence (32 WGs x 32 dims) + gx GEMM + weight conversions + xsum + tokfeat
  k_mega<<<256, 256, 0, stream>>>(eWhh, ebhh, xmb, wihb, ebih, gx, hw, xm,
                                  ttW, ttb, polW, polb, tf, ttpol,
                                  opW1, w1b, opW2, w2t, hsum, xsum, done, wm);

  // reductions + program generator
  k_csum<<<1, 64, 0, stream>>>(ttpol, csum);
  k_ctx<<<32, 256, 0, stream>>>(hsum, xsum, csum, c2hW, c2hb, pgh);
  for (int t = 0; t < 4; ++t)
    k_pg<<<128, 256, 0, stream>>>(pgWhh, pgbih, pgbhh, pgh + (size_t)t*8192, pgh + (size_t)(t+1)*8192);
  k_wlogits<<<1, 256, 0, stream>>>(pgh, prjW, prjb, plog, wv);
  k_obias<<<32, 256, 0, stream>>>(wv, opb2, obias);

  // op library fused
  { EpiArgs e{}; e.outh = h1g; e.bias = opb1; e.wvp = wv; e.ldc = 8192;
    k_gemm<1,false><<<dim3(32,64), 256, 0, stream>>>(tf, w1b, KP_, KP_, KP_, e); }
  { EpiArgs e{}; e.outf = outbuf; e.obias = obias; e.ldc = 1024;
    k_gemm<2,true><<<dim3(32,8), 256, 0, stream>>>(h1g, w2t, 8192, 8192, 8192, e); }

  // pooling + z + losses
  k_pool2<<<64, 128, 0, stream>>>(outbuf, pooled2);
  k_z<<<1024, 256, 0, stream>>>(pooled2, outW, outB, dout);
  k_losses<<<1, 64, 0, stream>>>(pooled2, plog, dout);
}

// Round 13
// 1629.649 us; speedup vs baseline: 1.0792x; 1.0792x over previous
//
#include <hip/hip_runtime.h>
#include <stdint.h>

// Model dims
#define D_   1024
#define T_   512
#define B_   8
#define V_   8
#define I_   1032
#define KP_  1088
#define TDK  3072
#define NGRU 64
#define NHELP 192

typedef __attribute__((ext_vector_type(8))) short bf16x8;
typedef __attribute__((ext_vector_type(4))) float f32x4;

__device__ __forceinline__ ushort f2bf(float f){
  union{ unsigned u; float f; } c; c.f = f;
  unsigned u = c.u;
  return (ushort)((u + 0x7FFFu + ((u>>16)&1u)) >> 16);   // RNE
}
__device__ __forceinline__ float bf2f(ushort h){
  union{ unsigned u; float f; } c; c.u = ((unsigned)h) << 16; return c.f;
}
__device__ __forceinline__ float sigmoidf_(float x){ return 1.f/(1.f+__expf(-x)); }

#define WAITV(N) do{ asm volatile("s_waitcnt vmcnt(" #N ")" ::: "memory"); __builtin_amdgcn_sched_barrier(0); }while(0)

__device__ __forceinline__ void gload_lds16(const void* g, void* l){
  __builtin_amdgcn_global_load_lds((const __attribute__((address_space(1))) void*)g,
                                   (__attribute__((address_space(3))) void*)l, 16, 0, 0);
}
__device__ __forceinline__ void st_dwordx2_sc(void* p, unsigned lo, unsigned hi){
  uint2 v; v.x = lo; v.y = hi;
  asm volatile("global_store_dwordx2 %0, %1, off sc0 sc1" :: "v"(p), "v"(v) : "memory");
}

// ---------------- prep: x*mask -> f32 + bf16 ----------------
__global__ __launch_bounds__(256) void k_prep(const float* __restrict__ x, const float* __restrict__ mask,
                                              float* __restrict__ xm, ushort* __restrict__ xmb){
  int i = blockIdx.x*256 + threadIdx.x;
  float4 v = ((const float4*)x)[i];
  float mk = mask[i >> 8];
  v.x*=mk; v.y*=mk; v.z*=mk; v.w*=mk;
  ((float4*)xm)[i] = v;
  ushort4 h; h.x=f2bf(v.x); h.y=f2bf(v.y); h.z=f2bf(v.z); h.w=f2bf(v.w);
  ((ushort4*)xmb)[i] = h;
}

// init h slot 0: value bf16(0), tag 1
__global__ __launch_bounds__(256) void k_hinit(unsigned* __restrict__ hw){
  hw[blockIdx.x*256 + threadIdx.x] = 1u;
}

__global__ __launch_bounds__(256) void k_cvt(const float* __restrict__ in, ushort* __restrict__ out, int n4){
  int i = blockIdx.x*256 + threadIdx.x;
  if (i < n4){
    float4 v = ((const float4*)in)[i];
    ushort4 h; h.x=f2bf(v.x); h.y=f2bf(v.y); h.z=f2bf(v.z); h.w=f2bf(v.w);
    ((ushort4*)out)[i] = h;
  }
}

// h1g *= wv[b][v]   (i indexes ushort4; elem e = i*4; row = e>>13 = i>>11; b = row>>9 = i>>20)
__global__ __launch_bounds__(256) void k_scale(ushort* __restrict__ h1g, const float* __restrict__ wv){
  const int i = blockIdx.x*256 + threadIdx.x;        // 0 .. 8M-1
  const int b = i >> 20;                             // FIX (R12): batch, not row
  const int v = (i >> 8) & 7;                        // col>>10
  const float s = wv[b*8 + v];
  ushort4 h = ((const ushort4*)h1g)[i];
  h.x = f2bf(bf2f(h.x)*s); h.y = f2bf(bf2f(h.y)*s);
  h.z = f2bf(bf2f(h.z)*s); h.w = f2bf(bf2f(h.w)*s);
  ((ushort4*)h1g)[i] = h;
}

// ---------------- bf16 MFMA GEMM (m97 structure) ----------------
struct EpiArgs {
  float* outf; ushort* outh;
  const float* bias; const float* wvp; const float* obias;
  int ldc;
};

template<int EPI, bool INIT>
__global__ __launch_bounds__(256) void k_gemm(const ushort* __restrict__ A, const ushort* __restrict__ Bm,
                                              int lda, int ldb, int K, EpiArgs e)
{
  __shared__ ushort As[128*64];
  __shared__ ushort Bs[128*64];
  const int tid = threadIdx.x;
  const int w = tid >> 6, l = tid & 63;
  const int wr = w >> 1, wc = w & 1;
  f32x4 acc[4][4] = {};
  const size_t arow = (size_t)(blockIdx.x*128);
  const size_t brow = (size_t)(blockIdx.y*128);
  const int lr = l >> 3, lcol = (l & 7) << 3;

  for (int k0 = 0; k0 < K; k0 += 64){
    __syncthreads();
    #pragma unroll
    for (int g = 0; g < 4; ++g){
      const int chunk = (g<<2) + w;
      const int row = (chunk<<3) + lr;
      gload_lds16(A + (arow + row)*lda + k0 + lcol, &As[chunk<<9]);
      gload_lds16(Bm + (brow + row)*ldb + k0 + lcol, &Bs[chunk<<9]);
    }
    __syncthreads();
    #pragma unroll
    for (int kk = 0; kk < 2; ++kk){
      bf16x8 af[4], bfr[4];
      #pragma unroll
      for (int m=0;m<4;++m) af[m]  = *(const bf16x8*)&As[(wr*64 + m*16 + (l&15))*64 + kk*32 + ((l>>4)<<3)];
      #pragma unroll
      for (int n=0;n<4;++n) bfr[n] = *(const bf16x8*)&Bs[(wc*64 + n*16 + (l&15))*64 + kk*32 + ((l>>4)<<3)];
      #pragma unroll
      for (int m=0;m<4;++m)
        #pragma unroll
        for (int n=0;n<4;++n)
          acc[m][n] = __builtin_amdgcn_mfma_f32_16x16x32_bf16(af[m], bfr[n], acc[m][n], 0, 0, 0);
    }
  }
  const int row0 = blockIdx.x*128 + wr*64 + ((l>>4)<<2);
  const int col0 = blockIdx.y*128 + wc*64 + (l&15);
  #pragma unroll
  for (int m=0;m<4;++m){
    #pragma unroll
    for (int n=0;n<4;++n){
      f32x4 a = acc[m][n];
      int col = col0 + n*16;
      #pragma unroll
      for (int q=0;q<4;++q){
        int row = row0 + m*16 + q;
        float val = a[q];
        if constexpr (EPI==1){
          float xg = val + e.bias[col];
          float g = 0.5f*xg*(1.0f + erff(xg*0.70710678118f));
          e.outh[(size_t)row*e.ldc + col] = f2bf(g * e.wvp[(row>>9)*V_ + (col>>10)]);
        } else {
          size_t idx = (size_t)row*e.ldc + col;
          float prev = INIT ? e.obias[((row>>9)<<10) + col] : e.outf[idx];
          e.outf[idx] = prev + val;
        }
      }
    }
  }
}

// ================= MEGA KERNEL (R7 GRU + streamed unweighted h1) =================
// ctrl: done[768] | wm@896 | tfdone@1024..5119 | w1done@5120..5151
__global__ __launch_bounds__(256, 1) void k_mega(
    const float* __restrict__ whh, const float* __restrict__ bhh,
    const ushort* __restrict__ xmb, const ushort* __restrict__ wihb,
    const float* __restrict__ ebih, float* __restrict__ gx,
    unsigned* __restrict__ hw, const float* __restrict__ xm,
    const float* __restrict__ ttW, const float* __restrict__ ttb,
    const float* __restrict__ polW, const float* __restrict__ polb,
    ushort* __restrict__ tf, float* __restrict__ ttpol,
    const float* __restrict__ opW1, ushort* __restrict__ w1b,
    const float* __restrict__ opW2, ushort* __restrict__ w2t,
    const float* __restrict__ opb1, ushort* __restrict__ h1g,
    float* __restrict__ hsum, float* __restrict__ xsum,
    int* __restrict__ done, int* __restrict__ wm,
    int* __restrict__ tfdone, int* __restrict__ w1done, int stream)
{
  __shared__ char smem[32768];
  const int tid = threadIdx.x;
  const int w = tid >> 6, l = tid & 63;

  if (blockIdx.x < NGRU){
    // ---------------- GRU path (exact R7) ----------------
    const int c = blockIdx.x;
    const int ar = l & 15, kg = (l >> 4) << 3;
    ushort (*Hld)[264] = (ushort (*)[264])smem;
    float* Red = (float*)(smem + 4*8*264*2);

    bf16x8 Bf[3][8];
    #pragma unroll
    for (int g = 0; g < 3; ++g){
      #pragma unroll
      for (int s = 0; s < 8; ++s){
        const float* src = whh + ((size_t)((g<<10) + (c<<4) + ar))*1024 + (w<<8) + (s<<5) + kg;
        float4 u0 = *(const float4*)src;
        float4 u1 = *(const float4*)(src + 4);
        bf16x8 f;
        f[0]=(short)f2bf(u0.x); f[1]=(short)f2bf(u0.y); f[2]=(short)f2bf(u0.z); f[3]=(short)f2bf(u0.w);
        f[4]=(short)f2bf(u1.x); f[5]=(short)f2bf(u1.y); f[6]=(short)f2bf(u1.z); f[7]=(short)f2bf(u1.w);
        Bf[g][s] = f;
      }
    }
    const int pb = (w << 1) + ((l >> 4) & 1);
    const int pi = l & 15;
    const int dg = (c << 4) + pi;
    const float bhr = bhh[dg], bhz = bhh[1024 + dg], bhn = bhh[2048 + dg];
    float hp = 0.f, hacc = 0.f;
    __syncthreads();

    // gate gx block 0
    {
      const int* dp = done + l*3;
      int f0, f1, f2;
      while (true){
        asm volatile("global_load_dword %0, %1, off sc0 sc1" : "=v"(f0) : "v"(dp)   : "memory");
        asm volatile("global_load_dword %0, %1, off sc0 sc1" : "=v"(f1) : "v"(dp+1) : "memory");
        asm volatile("global_load_dword %0, %1, off sc0 sc1" : "=v"(f2) : "v"(dp+2) : "memory");
        WAITV(0);
        if (__all((f0 & f1 & f2) == 1)) break;
        __builtin_amdgcn_s_sleep(4);
      }
    }
    __syncthreads();
    float xr, xz, xn, nxr, nxz, nxn;
    if (l < 32){
      const float* g0 = gx + ((size_t)(pb*512))*TDK + dg;
      asm volatile("global_load_dword %0, %1, off sc0 sc1" : "=v"(xr) : "v"(g0)        : "memory");
      asm volatile("global_load_dword %0, %1, off sc0 sc1" : "=v"(xz) : "v"(g0 + 1024) : "memory");
      asm volatile("global_load_dword %0, %1, off sc0 sc1" : "=v"(xn) : "v"(g0 + 2048) : "memory");
    }
    WAITV(0);

    for (int t = 0; t < 512; ++t){
      if ((t & 127) == 0 && t){
        const int tq = t >> 7;
        const int* dp = done + tq*192 + l*3;
        int f0, f1, f2;
        while (true){
          asm volatile("global_load_dword %0, %1, off sc0 sc1" : "=v"(f0) : "v"(dp)   : "memory");
          asm volatile("global_load_dword %0, %1, off sc0 sc1" : "=v"(f1) : "v"(dp+1) : "memory");
          asm volatile("global_load_dword %0, %1, off sc0 sc1" : "=v"(f2) : "v"(dp+2) : "memory");
          WAITV(0);
          if (__all((f0 & f1 & f2) == 1)) break;
          __builtin_amdgcn_s_sleep(4);
        }
        __syncthreads();
        if (l < 32){
          const float* g0 = gx + ((size_t)(pb*512 + t))*TDK + dg;
          asm volatile("global_load_dword %0, %1, off sc0 sc1" : "=v"(xr) : "v"(g0)        : "memory");
          asm volatile("global_load_dword %0, %1, off sc0 sc1" : "=v"(xz) : "v"(g0 + 1024) : "memory");
          asm volatile("global_load_dword %0, %1, off sc0 sc1" : "=v"(xn) : "v"(g0 + 2048) : "memory");
        }
        WAITV(0);
      }
      uint4 rw[8];
      unsigned ok = 0;
      const unsigned tagv = (unsigned)(t + 1);
      const unsigned* qb = hw + ((size_t)t << 13) + (w << 8) + (l << 2);
      #pragma unroll
      for (int j = 0; j < 8; ++j)
        asm volatile("global_load_dwordx4 %0, %1, off sc0 sc1" : "=v"(rw[j]) : "v"(qb + (j << 10)) : "memory");
      const bool gxi = (((t+1) & 127) != 0) && (t+1 < 512);
      if (gxi && l < 32){
        const float* g0 = gx + ((size_t)(pb*512 + t + 1))*TDK + dg;
        asm volatile("global_load_dword %0, %1, off sc0 sc1" : "=v"(nxr) : "v"(g0)        : "memory");
        asm volatile("global_load_dword %0, %1, off sc0 sc1" : "=v"(nxz) : "v"(g0 + 1024) : "memory");
        asm volatile("global_load_dword %0, %1, off sc0 sc1" : "=v"(nxn) : "v"(g0 + 2048) : "memory");
      }
      if (gxi) { WAITV(3); } else { WAITV(0); }
      #pragma unroll
      for (int j = 0; j < 8; ++j){
        unsigned m = (rw[j].x ^ tagv) | (rw[j].y ^ tagv) | (rw[j].z ^ tagv) | (rw[j].w ^ tagv);
        if ((m & 0xFFFFu) == 0u) ok |= (1u << j);
      }
      while (!__all(ok == 0xFFu)){
        #pragma unroll
        for (int j = 0; j < 8; ++j){
          if (!(ok & (1u << j)))
            asm volatile("global_load_dwordx4 %0, %1, off sc0 sc1" : "=v"(rw[j]) : "v"(qb + (j << 10)) : "memory");
        }
        WAITV(0);
        #pragma unroll
        for (int j = 0; j < 8; ++j){
          if (!(ok & (1u << j))){
            unsigned m = (rw[j].x ^ tagv) | (rw[j].y ^ tagv) | (rw[j].z ^ tagv) | (rw[j].w ^ tagv);
            if ((m & 0xFFFFu) == 0u) ok |= (1u << j);
          }
        }
      }
      #pragma unroll
      for (int j = 0; j < 8; ++j){
        unsigned d0 = __builtin_amdgcn_perm(rw[j].y, rw[j].x, 0x07060302u);
        unsigned d1 = __builtin_amdgcn_perm(rw[j].w, rw[j].z, 0x07060302u);
        union { unsigned u[2]; unsigned long long ull; } cv; cv.u[0]=d0; cv.u[1]=d1;
        *(unsigned long long*)&Hld[w*8 + j][l<<2] = cv.ull;
      }
      f32x4 ac0 = {0.f,0.f,0.f,0.f}, ac1 = {0.f,0.f,0.f,0.f}, ac2 = {0.f,0.f,0.f,0.f};
      #pragma unroll
      for (int s = 0; s < 8; ++s){
        bf16x8 af = *(const bf16x8*)&Hld[w*8 + (ar & 7)][(s << 5) + kg];
        ac0 = __builtin_amdgcn_mfma_f32_16x16x32_bf16(af, Bf[0][s], ac0, 0, 0, 0);
        ac1 = __builtin_amdgcn_mfma_f32_16x16x32_bf16(af, Bf[1][s], ac1, 0, 0, 0);
        ac2 = __builtin_amdgcn_mfma_f32_16x16x32_bf16(af, Bf[2][s], ac2, 0, 0, 0);
      }
      const int cur = t & 1;
      if (l < 32){
        *(f32x4*)(&Red[cur*1536 + (w*3+0)*128 + l*4]) = ac0;
        *(f32x4*)(&Red[cur*1536 + (w*3+1)*128 + l*4]) = ac1;
        *(f32x4*)(&Red[cur*1536 + (w*3+2)*128 + l*4]) = ac2;
      }
      __syncthreads();
      if (l < 32){
        const int idx = (((pb>>2)<<4) | pi)*4 + (pb & 3);
        const float* R = Red + cur*1536;
        float ghr = R[idx]       + R[384 + idx]  + R[768 + idx]  + R[1152 + idx];
        float ghz = R[128 + idx] + R[512 + idx]  + R[896 + idx]  + R[1280 + idx];
        float ghn = R[256 + idx] + R[640 + idx]  + R[1024 + idx] + R[1408 + idx];
        float r  = sigmoidf_(xr + ghr + bhr);
        float z  = sigmoidf_(xz + ghz + bhz);
        float nn = tanhf(xn + r*(ghn + bhn));
        hp = (1.f - z)*nn + z*hp;
        hacc += hp;
        unsigned word = (((unsigned)f2bf(hp)) << 16) | (unsigned)(t + 2);
        unsigned* hdst = hw + ((size_t)(t+1) << 13) + (pb << 10) + dg;
        asm volatile("global_store_dword %0, %1, off sc0 sc1" :: "v"(hdst), "v"(word) : "memory");
      }
      if (c == 0 && tid == 0){
        asm volatile("global_store_dword %0, %1, off sc0 sc1" :: "v"(wm), "v"(t) : "memory");
      }
      if (gxi && l < 32){ xr = nxr; xz = nxz; xn = nxn; }
    }
    if (l < 32) hsum[(pb << 10) + dg] = hacc;
    return;
  }

  // ---------------- helper path ----------------
  const int hid = blockIdx.x - NGRU;            // 0..191
  ushort* As = (ushort*)smem;
  ushort* Bs = As + 8192;

  // phase 1: gx GEMM tiles in t-priority order (all 192 helpers)
  {
    const int bb = hid / 24, ni = hid % 24;
    const int wr_ = w >> 1, wc_ = w & 1;
    const int lr = l >> 3, lcol = (l & 7) << 3;
    for (int wv = 0; wv < 4; ++wv){
      const int mi = bb*4 + wv;
      f32x4 acc[4][4] = {};
      for (int k0 = 0; k0 < 1024; k0 += 64){
        __syncthreads();
        #pragma unroll
        for (int g = 0; g < 4; ++g){
          const int chunk = (g<<2) + w;
          const int row = (chunk<<3) + lr;
          gload_lds16(xmb + (size_t)(mi*128 + row)*1024 + k0 + lcol, &As[chunk<<9]);
          gload_lds16(wihb + (size_t)(ni*128 + row)*1024 + k0 + lcol, &Bs[chunk<<9]);
        }
        __syncthreads();
        #pragma unroll
        for (int kk = 0; kk < 2; ++kk){
          bf16x8 af[4], bfr[4];
          #pragma unroll
          for (int m=0;m<4;++m) af[m]  = *(const bf16x8*)&As[(wr_*64 + m*16 + (l&15))*64 + kk*32 + ((l>>4)<<3)];
          #pragma unroll
          for (int n=0;n<4;++n) bfr[n] = *(const bf16x8*)&Bs[(wc_*64 + n*16 + (l&15))*64 + kk*32 + ((l>>4)<<3)];
          #pragma unroll
          for (int m=0;m<4;++m)
            #pragma unroll
            for (int n=0;n<4;++n)
              acc[m][n] = __builtin_amdgcn_mfma_f32_16x16x32_bf16(af[m], bfr[n], acc[m][n], 0, 0, 0);
        }
      }
      const int row0 = mi*128 + wr_*64 + ((l>>4)<<2);
      const int col0 = ni*128 + wc_*64 + (l&15);
      #pragma unroll
      for (int m=0;m<4;++m){
        #pragma unroll
        for (int n=0;n<4;++n){
          f32x4 a = acc[m][n];
          int col = col0 + n*16;
          float bi = ebih[col];
          #pragma unroll
          for (int q=0;q<4;++q){
            int row = row0 + m*16 + q;
            float val = a[q] + bi;
            float* p = gx + (size_t)row*TDK + col;
            asm volatile("global_store_dword %0, %1, off sc0 sc1" :: "v"(p), "v"(val) : "memory");
          }
        }
      }
      WAITV(0);
      __syncthreads();
      if (tid == 0){
        int one = 1;
        const int* fp = done + wv*192 + hid;
        asm volatile("global_store_dword %0, %1, off sc0 sc1" :: "v"(fp), "v"(one) : "memory");
      }
      __syncthreads();
    }
  }
  // phase 2a: w1b (helpers 160..191, sc0sc1 write-through + flag)
  if (hid >= 160){
    for (int row = hid - 160; row < 8192; row += 32){
      const float* src = opW1 + (size_t)row*I_;
      ushort* dst = w1b + (size_t)row*KP_;
      for (int c0 = tid*4; c0 < KP_; c0 += 1024){
        ushort4 h;
        h.x = (c0   < I_) ? f2bf(src[c0])   : (ushort)0;
        h.y = (c0+1 < I_) ? f2bf(src[c0+1]) : (ushort)0;
        h.z = (c0+2 < I_) ? f2bf(src[c0+2]) : (ushort)0;
        h.w = (c0+3 < I_) ? f2bf(src[c0+3]) : (ushort)0;
        unsigned lo = ((unsigned)h.y << 16) | h.x;
        unsigned hi = ((unsigned)h.w << 16) | h.z;
        st_dwordx2_sc(dst + c0, lo, hi);
      }
    }
    WAITV(0);
    __syncthreads();
    if (tid == 0){
      int one = 1;
      const int* fp = w1done + (hid - 160);
      asm volatile("global_store_dword %0, %1, off sc0 sc1" :: "v"(fp), "v"(one) : "memory");
    }
  }
  // phase 2b: w2t (helpers 128..159, plain — consumed post-kernel)
  if (hid >= 128 && hid < 160){
    for (int blk = hid - 128; blk < 8192; blk += 32){
      const int v = blk >> 10, d = blk & 1023;
      const float4* src = (const float4*)(opW2 + ((size_t)(v*1024 + d))*1024);
      ushort* dst = w2t + (size_t)d*8192 + v*1024;
      float4 u = src[tid];
      ushort4 h; h.x=f2bf(u.x); h.y=f2bf(u.y); h.z=f2bf(u.z); h.w=f2bf(u.w);
      ((ushort4*)dst)[tid] = h;
    }
  }
  // phase 3: xsum
  if (hid < 32){
    const int o = hid*256 + tid;
    const int b = o >> 10, d = o & 1023;
    float s = 0.f;
    for (int t = 0; t < 512; ++t) s += xm[((size_t)(b*512 + t) << 10) + d];
    xsum[o] = s;
  }
  // phase 4+5: t-ordered interleave of tokfeat and streamed h1 tiles
  for (int tb = 0; tb < 4; ++tb){
    // --- tokfeat for t in [tb*128, tb*128+128) ---
    {
      float* xe = (float*)smem;
      for (int idx = tb*1024 + hid; idx < (tb+1)*1024; idx += NHELP){
        const int t = idx >> 3, b = idx & 7;
        const int tok = b*512 + t;
        const int need = (t+1 < 511) ? (t+1) : 511;
        if (tid == 0){
          int wmv;
          while (true){
            asm volatile("global_load_dword %0, %1, off sc0 sc1" : "=v"(wmv) : "v"(wm) : "memory");
            asm volatile("s_waitcnt vmcnt(0)" ::: "memory");
            if (wmv >= need) break;
            __builtin_amdgcn_s_sleep(64);
          }
        }
        __syncthreads();
        const unsigned tagv = (unsigned)(t + 2);
        const unsigned* src = hw + ((size_t)(t+1) << 13) + (b << 10) + (tid << 2);
        uint4 hv;
        while (true){
          asm volatile("global_load_dwordx4 %0, %1, off sc0 sc1" : "=v"(hv) : "v"(src) : "memory");
          WAITV(0);
          unsigned m = (hv.x ^ tagv) | (hv.y ^ tagv) | (hv.z ^ tagv) | (hv.w ^ tagv);
          if (__syncthreads_and((int)((m & 0xFFFFu) == 0u))) break;
          __builtin_amdgcn_s_sleep(16);
        }
        float4 xv = ((const float4*)(xm + (size_t)tok*1024))[tid];
        float4 ev;
        ev.x = bf2f((ushort)(hv.x >> 16)) + xv.x;
        ev.y = bf2f((ushort)(hv.y >> 16)) + xv.y;
        ev.z = bf2f((ushort)(hv.z >> 16)) + xv.z;
        ev.w = bf2f((ushort)(hv.w >> 16)) + xv.w;
        *(float4*)&xe[tid*4] = ev;
        ushort4 eb; eb.x=f2bf(ev.x); eb.y=f2bf(ev.y); eb.z=f2bf(ev.z); eb.w=f2bf(ev.w);
        {
          unsigned lo = ((unsigned)eb.y << 16) | eb.x;
          unsigned hi = ((unsigned)eb.w << 16) | eb.z;
          st_dwordx2_sc(&tf[(size_t)tok*KP_ + tid*4], lo, hi);
        }
        __syncthreads();
        const int j = tid >> 5, ln = tid & 31;
        const float* Wr = (j < 6) ? (ttW + j*1024) : (polW + (j-6)*1024);
        float acc = 0.f;
        for (int k = ln; k < 1024; k += 32) acc += xe[k]*Wr[k];
        #pragma unroll
        for (int m=16; m>=1; m>>=1) acc += __shfl_xor(acc, m, 32);
        if (ln == 0){
          float val = acc + ((j<6)? ttb[j] : polb[j-6]);
          ttpol[(size_t)tok*8 + j] = val;
          ushort hv2 = f2bf(val);
          asm volatile("global_store_short %0, %1, off sc0 sc1" :: "v"(&tf[(size_t)tok*KP_ + 1024 + j]), "v"((unsigned)hv2) : "memory");
        }
        if (tid < 56){
          asm volatile("global_store_short %0, %1, off sc0 sc1" :: "v"(&tf[(size_t)tok*KP_ + 1032 + tid]), "v"(0u) : "memory");
        }
        WAITV(0);
        __syncthreads();
        if (tid == 0){
          int one = 1;
          asm volatile("global_store_dword %0, %1, off sc0 sc1" :: "v"(tfdone + idx), "v"(one) : "memory");
        }
        __syncthreads();
      }
    }
    // --- streamed h1 tiles for this tb: unit u2 = b*64 + n (sc0sc1 reg-staged A/B) ---
    if (stream){
      const int wr_ = w >> 1, wc_ = w & 1;
      const int lr = l >> 3, lcol = (l & 7) << 3;
      for (int u2 = hid; u2 < 512; u2 += NHELP){
        const int b = u2 >> 6, n = u2 & 63;
        // gate: w1done[0..31] (tids 0..31) + tfdone for 128 tokens of (b, tb) (tids 32..159)
        {
          while (true){
            int f0 = 1;
            if (tid < 32){
              asm volatile("global_load_dword %0, %1, off sc0 sc1" : "=v"(f0) : "v"(w1done + tid) : "memory");
              asm volatile("s_waitcnt vmcnt(0)" ::: "memory");
            } else if (tid < 160){
              const int idx = (tb*128 + (tid - 32))*8 + b;
              asm volatile("global_load_dword %0, %1, off sc0 sc1" : "=v"(f0) : "v"(tfdone + idx) : "memory");
              asm volatile("s_waitcnt vmcnt(0)" ::: "memory");
            }
            if (__syncthreads_and((int)(f0 == 1))) break;
            __builtin_amdgcn_s_sleep(16);
          }
        }
        // GEMM: M=128 rows (tok b*512 + tb*128 + r), N-tile n, K=KP_
        // A/B staged via sc0sc1 register loads (L2-bypass: tf/w1b were written cross-WG in-kernel)
        const size_t arow = (size_t)(b*512 + tb*128);
        const size_t brow = (size_t)(n*128);
        f32x4 acc[4][4] = {};
        for (int k0 = 0; k0 < KP_; k0 += 64){
          __syncthreads();
          uint4 va[4], vb[4];
          #pragma unroll
          for (int g = 0; g < 4; ++g){
            const int chunk = (g<<2) + w;
            const int row = (chunk<<3) + lr;
            const ushort* pa = tf  + (arow + row)*KP_ + k0 + lcol;
            const ushort* pb = w1b + (brow + row)*KP_ + k0 + lcol;
            asm volatile("global_load_dwordx4 %0, %1, off sc0 sc1" : "=v"(va[g]) : "v"(pa) : "memory");
            asm volatile("global_load_dwordx4 %0, %1, off sc0 sc1" : "=v"(vb[g]) : "v"(pb) : "memory");
          }
          WAITV(0);
          #pragma unroll
          for (int g = 0; g < 4; ++g){
            const int chunk = (g<<2) + w;
            *(uint4*)&As[(chunk<<9) + l*8] = va[g];
            *(uint4*)&Bs[(chunk<<9) + l*8] = vb[g];
          }
          __syncthreads();
          #pragma unroll
          for (int kk = 0; kk < 2; ++kk){
            bf16x8 af[4], bfr[4];
            #pragma unroll
            for (int m=0;m<4;++m) af[m]  = *(const bf16x8*)&As[(wr_*64 + m*16 + (l&15))*64 + kk*32 + ((l>>4)<<3)];
            #pragma unroll
            for (int nn=0;nn<4;++nn) bfr[nn] = *(const bf16x8*)&Bs[(wc_*64 + nn*16 + (l&15))*64 + kk*32 + ((l>>4)<<3)];
            #pragma unroll
            for (int m=0;m<4;++m)
              #pragma unroll
              for (int nn=0;nn<4;++nn)
                acc[m][nn] = __builtin_amdgcn_mfma_f32_16x16x32_bf16(af[m], bfr[nn], acc[m][nn], 0, 0, 0);
          }
        }
        const int row0 = (int)arow + wr_*64 + ((l>>4)<<2);
        const int col0 = (int)brow + wc_*64 + (l&15);
        #pragma unroll
        for (int m=0;m<4;++m){
          #pragma unroll
          for (int nn=0;nn<4;++nn){
            f32x4 a = acc[m][nn];
            int col = col0 + nn*16;
            float bi = opb1[col];
            #pragma unroll
            for (int q=0;q<4;++q){
              int row = row0 + m*16 + q;
              float xg = a[q] + bi;
              float g = 0.5f*xg*(1.0f + erff(xg*0.70710678118f));
              h1g[(size_t)row*8192 + col] = f2bf(g);       // unweighted; plain store
            }
          }
        }
        __syncthreads();
      }
    }
  }
}

__global__ __launch_bounds__(64) void k_csum(const float* __restrict__ ttpol, float* __restrict__ csum){
  const int b = threadIdx.x >> 3, j = threadIdx.x & 7;
  float s = 0.f;
  for (int t=0; t<512; ++t) s += ttpol[((size_t)(b*512+t)<<3) + j];
  csum[threadIdx.x] = s * (1.f/512.f);
}

__global__ __launch_bounds__(256) void k_ctx(const float* __restrict__ hsum, const float* __restrict__ xsum,
                                             const float* __restrict__ csum,
                                             const float* __restrict__ c2hW, const float* __restrict__ c2hb,
                                             float* __restrict__ pgh0){
  const int i = blockIdx.x*256 + threadIdx.x;
  const int b = i >> 10, d = i & 1023;
  const float* wr = c2hW + (size_t)d*I_;
  const float* hs = hsum + (b<<10);
  const float* xs = xsum + (b<<10);
  float s = 0.f;
  for (int k=0; k<1024; ++k) s += (hs[k]+xs[k])*wr[k];
  float acc = c2hb[d] + s*(1.f/512.f);
  #pragma unroll
  for (int k=0; k<8; ++k) acc += csum[b*8+k]*wr[1024+k];
  pgh0[i] = acc;
}

__global__ __launch_bounds__(256) void k_pg(const float* __restrict__ whh, const float* __restrict__ bih,
                                            const float* __restrict__ bhh, const float* __restrict__ hin,
                                            float* __restrict__ hout){
  __shared__ float sh[8][1024];
  const int tid = threadIdx.x;
  for (int f = tid; f < 2048; f += 256) ((float4*)&sh[0][0])[f] = ((const float4*)hin)[f];
  __syncthreads();
  const int d = blockIdx.x*8 + (tid>>5), ln = tid & 31;
  const float* wr = whh + (size_t)d*1024;
  const float* wz = whh + (size_t)(1024+d)*1024;
  const float* wn = whh + (size_t)(2048+d)*1024;
  float ar[8]={0,0,0,0,0,0,0,0}, az[8]={0,0,0,0,0,0,0,0}, an[8]={0,0,0,0,0,0,0,0};
  for (int k = ln; k < 1024; k += 32){
    float r_=wr[k], z_=wz[k], n_=wn[k];
    #pragma unroll
    for (int b=0;b<8;++b){ float h = sh[b][k]; ar[b]+=h*r_; az[b]+=h*z_; an[b]+=h*n_; }
  }
  #pragma unroll
  for (int m=16; m>=1; m>>=1){
    #pragma unroll
    for (int b=0;b<8;++b){ ar[b]+=__shfl_xor(ar[b],m,32); az[b]+=__shfl_xor(az[b],m,32); an[b]+=__shfl_xor(an[b],m,32); }
  }
  if (ln == 0){
    float xr=bih[d], xz=bih[1024+d], xn=bih[2048+d];
    float br=bhh[d], bz=bhh[1024+d], bn=bhh[2048+d];
    #pragma unroll
    for (int b=0;b<8;++b){
      float r = sigmoidf_(xr + ar[b] + br);
      float z = sigmoidf_(xz + az[b] + bz);
      float nn = tanhf(xn + r*(an[b] + bn));
      hout[(b<<10)+d] = (1.f - z)*nn + z*sh[b][d];
    }
  }
}

__global__ __launch_bounds__(256) void k_wlogits(const float* __restrict__ pgh, const float* __restrict__ prjW,
                                                 const float* __restrict__ prjb, float* __restrict__ plog,
                                                 float* __restrict__ wv){
  __shared__ float lg[256];
  __shared__ float sm[256];
  const int tid = threadIdx.x;
  const int b = tid>>5, li = (tid>>3)&3, v = tid&7;
  const float* h = pgh + (size_t)(li+1)*8192 + (b<<10);
  const float* pw = prjW + (v<<10);
  float acc = prjb[v];
  for (int k=0;k<1024;++k) acc += h[k]*pw[k];
  lg[tid] = acc;
  plog[tid] = acc;
  __syncthreads();
  if (tid < 32){
    const int bb = tid>>2, ll = tid&3;
    const float* row = &lg[bb*32 + ll*8];
    float mx = row[0];
    #pragma unroll
    for (int u=1;u<8;++u) mx = fmaxf(mx, row[u]);
    float e[8], s=0.f;
    #pragma unroll
    for (int u=0;u<8;++u){ e[u]=__expf(row[u]-mx); s+=e[u]; }
    #pragma unroll
    for (int u=0;u<8;++u) sm[(bb*4+ll)*8+u] = e[u]/s;
  }
  __syncthreads();
  if (tid < 64){
    const int bb = tid>>3, u = tid&7;
    float s = sm[(bb*4+0)*8+u] + sm[(bb*4+1)*8+u] + sm[(bb*4+2)*8+u] + sm[(bb*4+3)*8+u];
    wv[bb*8+u] = 0.25f*s;
  }
}

__global__ __launch_bounds__(256) void k_obias(const float* __restrict__ wv, const float* __restrict__ opb2,
                                               float* __restrict__ obias){
  const int i = blockIdx.x*256 + threadIdx.x;
  const int b = i>>10, d = i&1023;
  float s = 0.f;
  #pragma unroll
  for (int v=0; v<8; ++v) s += wv[b*8+v]*opb2[(v<<10)+d];
  obias[i] = s;
}

__global__ __launch_bounds__(128) void k_pool2(const float* __restrict__ outb, float* __restrict__ pooled2){
  const int b = blockIdx.x >> 3;
  const int col = ((blockIdx.x & 7) << 7) + threadIdx.x;
  float mx = -3.4e38f, sm = 0.f;
  for (int t=0; t<512; ++t){
    float v = outb[((size_t)(b*512+t)<<10) + col];
    mx = fmaxf(mx, v); sm += v;
  }
  pooled2[((size_t)b<<11) + col] = mx;
  pooled2[((size_t)b<<11) + 1024 + col] = sm*(1.f/512.f);
}

__global__ __launch_bounds__(256) void k_z(const float* __restrict__ pooled2, const float* __restrict__ outW,
                                           const float* __restrict__ outBias, float* __restrict__ dout){
  __shared__ float p2[2048];
  const int o = blockIdx.x << 3;
  const int b = o >> 10, dbase = o & 1023;
  for (int f = threadIdx.x; f < 512; f += 256)
    ((float4*)p2)[f] = ((const float4*)(pooled2 + ((size_t)b<<11)))[f];
  __syncthreads();
  const int g = threadIdx.x >> 5, ln = threadIdx.x & 31;
  const int d = dbase + g;
  const float* wr = outW + ((size_t)d << 11);
  float acc = 0.f;
  for (int k = ln; k < 2048; k += 32) acc += p2[k]*wr[k];
  #pragma unroll
  for (int m=16; m>=1; m>>=1) acc += __shfl_xor(acc, m, 32);
  if (ln == 0) dout[(b<<10) + d] = acc + outBias[d];
}

__global__ __launch_bounds__(64) void k_losses(const float* __restrict__ p2g, const float* __restrict__ plog,
                                               float* __restrict__ dout){
  __shared__ float p2n[8], sq[8], pn[8];
  const int l = threadIdx.x;
  { const int b=l>>3, p=l&7; float s=0.f;
    const float* row = p2g + ((size_t)b<<11) + (p<<8);
    for (int k=0;k<256;++k){ float v=row[k]; s += v*v; }
    s += __shfl_xor(s,4,8); s += __shfl_xor(s,2,8); s += __shfl_xor(s,1,8);
    if (p==0) p2n[b] = fmaxf(sqrtf(s), 1e-12f);
  }
  if (l < 8){
    float s=0.f;
    #pragma unroll
    for (int k=0;k<32;++k){ float v=plog[l*32+k]; s+=v*v; }
    sq[l]=s; pn[l]=fmaxf(sqrtf(s),1e-12f);
  }
  __syncthreads();
  const int i=l>>3, j=l&7;
  const float* ri = p2g + ((size_t)i<<11);
  const float* rj = p2g + ((size_t)j<<11);
  float dot=0.f; for (int k=0;k<2048;++k) dot += ri[k]*rj[k];
  float sim = dot/(p2n[i]*p2n[j]);
  float pd=0.f;
  #pragma unroll
  for (int k=0;k<32;++k) pd += plog[i*32+k]*plog[j*32+k];
  float d2 = fmaxf(sq[i]+sq[j]-2.f*pd, 0.f);
  float dist = (d2>0.f)? sqrtf(d2) : 0.f;
  float psim = pd/(pn[i]*pn[j]);
  float pos = (sim>0.7f)?1.f:0.f, neg = (sim<0.7f)?1.f:0.f;
  float rs = sim*dist, ps=(1.f-psim)*pos, ns=fmaxf(psim-0.5f,0.f)*neg, pc=pos, nc=neg;
  #pragma unroll
  for (int m=32; m>=1; m>>=1){
    rs+=__shfl_xor(rs,m); ps+=__shfl_xor(ps,m); ns+=__shfl_xor(ns,m);
    pc+=__shfl_xor(pc,m); nc+=__shfl_xor(nc,m);
  }
  if (l==0){ dout[8192]=rs*(1.f/64.f); dout[8193]=(ps+ns)/(pc+nc+1e-6f); }
}

// ============================ host ============================
extern "C" void kernel_launch(void* const* d_in, const int* in_sizes, int n_in,
                              void* d_out, int out_size, void* d_ws, size_t ws_size,
                              hipStream_t stream) {
  (void)in_sizes; (void)n_in; (void)out_size;
  const float* x     = (const float*)d_in[0];
  const float* amask = (const float*)d_in[1];
  const float* eWih  = (const float*)d_in[2];
  const float* eWhh  = (const float*)d_in[3];
  const float* ebih  = (const float*)d_in[4];
  const float* ebhh  = (const float*)d_in[5];
  const float* ttW   = (const float*)d_in[6];
  const float* ttb   = (const float*)d_in[7];
  const float* polW  = (const float*)d_in[8];
  const float* polb  = (const float*)d_in[9];
  const float* c2hW  = (const float*)d_in[10];
  const float* c2hb  = (const float*)d_in[11];
  const float* pgWhh = (const float*)d_in[13];
  const float* pgbih = (const float*)d_in[14];
  const float* pgbhh = (const float*)d_in[15];
  const float* prjW  = (const float*)d_in[16];
  const float* prjb  = (const float*)d_in[17];
  const float* opW1  = (const float*)d_in[18];
  const float* opb1  = (const float*)d_in[19];
  const float* opW2  = (const float*)d_in[20];
  const float* opb2  = (const float*)d_in[21];
  const float* outW  = (const float*)d_in[22];
  const float* outB  = (const float*)d_in[23];
  float* dout = (float*)d_out;

  char* ws = (char*)d_ws;
  size_t off = 0;
  auto alloc = [&](size_t bytes)->void*{ void* p = ws + off; off += (bytes + 255) & ~(size_t)255; return p; };
  char*     R       = (char*)   alloc(64ULL*1024*1024);   // xm(16M)+gx(48M)
  float*    xm      = (float*)  R;
  float*    gx      = (float*) (R + 16ULL*1024*1024);
  ushort*   xmb     = (ushort*)  alloc(4096ULL*1024*2);
  ushort*   wihb    = (ushort*)  alloc(3072ULL*1024*2);
  unsigned* hw      = (unsigned*)alloc(513ULL*8192*4);
  float*    ttpol   = (float*)   alloc(4096ULL*8*4);
  ushort*   tf      = (ushort*)  alloc(4096ULL*KP_*2);
  ushort*   w1b     = (ushort*)  alloc(8ULL*1024*KP_*2);
  ushort*   w2t     = (ushort*)  alloc(1024ULL*8192*2);
  float*    outbuf  = (float*)   alloc(4096ULL*1024*4);
  float*    hsum    = (float*)   alloc(8192*4);
  float*    xsum    = (float*)   alloc(8192*4);
  float*    csum    = (float*)   alloc(64*4);
  float*    pgh     = (float*)   alloc(5ULL*8192*4);
  float*    plog    = (float*)   alloc(256*4);
  float*    wv      = (float*)   alloc(64*4);
  float*    obias   = (float*)   alloc(8192*4);
  float*    pooled2 = (float*)   alloc(16384*4);
  int*      ctrl    = (int*)     alloc(32768);
  int*      done    = ctrl;                     // [768]
  int*      wm      = ctrl + 896;
  int*      tfdone  = ctrl + 1024;              // [4096]
  int*      w1done  = ctrl + 5120;              // [32]
  // streamed-h1 buffer (64 MB) if workspace allows; else fall back to R-aliased weighted path
  const int do_stream = (ws_size >= off + 64ULL*1024*1024 + (1<<20)) ? 1 : 0;
  ushort*   h1g     = do_stream ? (ushort*)alloc(4096ULL*8192*2) : (ushort*)R;

  // control init + exchange-buffer init
  hipMemsetAsync(ctrl, 0, 5152*4, stream);      // done+tfdone+w1done
  hipMemsetAsync(wm, 0xFF, 4, stream);          // wm = -1
  k_hinit<<<32, 256, 0, stream>>>(hw);          // slot 0: value 0, tag 1
  k_prep<<<4096, 256, 0, stream>>>(x, amask, xm, xmb);
  k_cvt<<<3072, 256, 0, stream>>>(eWih, wihb, 3072*1024/4);

  // MEGA: recurrence + gx GEMM + w1b/w2t conversion + xsum + tokfeat + streamed h1
  k_mega<<<256, 256, 0, stream>>>(eWhh, ebhh, xmb, wihb, ebih, gx, hw, xm,
                                  ttW, ttb, polW, polb, tf, ttpol,
                                  opW1, w1b, opW2, w2t, opb1, h1g,
                                  hsum, xsum, done, wm, tfdone, w1done, do_stream);

  // reductions + program generator
  k_csum<<<1, 64, 0, stream>>>(ttpol, csum);
  k_ctx<<<32, 256, 0, stream>>>(hsum, xsum, csum, c2hW, c2hb, pgh);
  for (int t = 0; t < 4; ++t)
    k_pg<<<128, 256, 0, stream>>>(pgWhh, pgbih, pgbhh, pgh + (size_t)t*8192, pgh + (size_t)(t+1)*8192);
  k_wlogits<<<1, 256, 0, stream>>>(pgh, prjW, prjb, plog, wv);
  k_obias<<<32, 256, 0, stream>>>(wv, opb2, obias);

  if (do_stream){
    // h1 already computed (unweighted) under the gru shadow; apply wv then out-GEMM
    k_scale<<<32768, 256, 0, stream>>>(h1g, wv);
  } else {
    // fallback: weighted h1 in tail (h1g aliases R; xm/gx dead by now)
    EpiArgs e1{}; e1.outh = h1g; e1.bias = opb1; e1.wvp = wv; e1.ldc = 8192;
    k_gemm<1,false><<<dim3(32,64), 256, 0, stream>>>(tf, w1b, KP_, KP_, KP_, e1);
  }
  { EpiArgs e2{}; e2.outf = outbuf; e2.obias = obias; e2.ldc = 1024;
    k_gemm<2,true><<<dim3(32,8), 256, 0, stream>>>(h1g, w2t, 8192, 8192, 8192, e2); }

  // pooling + z + losses
  k_pool2<<<64, 128, 0, stream>>>(outbuf, pooled2);
  k_z<<<1024, 256, 0, stream>>>(pooled2, outW, outB, dout);
  k_losses<<<1, 64, 0, stream>>>(pooled2, plog, dout);
}

// Round 14
// 1569.297 us; speedup vs baseline: 1.1207x; 1.0385x over previous
//
#include <hip/hip_runtime.h>
#include <stdint.h>

// Model dims
#define D_   1024
#define T_   512
#define B_   8
#define V_   8
#define I_   1032
#define KP_  1088
#define TDK  3072
#define NGRU 64
#define NHELP 192

typedef __attribute__((ext_vector_type(8))) short bf16x8;
typedef __attribute__((ext_vector_type(4))) float f32x4;

__device__ __forceinline__ ushort f2bf(float f){
  union{ unsigned u; float f; } c; c.f = f;
  unsigned u = c.u;
  return (ushort)((u + 0x7FFFu + ((u>>16)&1u)) >> 16);   // RNE
}
__device__ __forceinline__ float bf2f(ushort h){
  union{ unsigned u; float f; } c; c.u = ((unsigned)h) << 16; return c.f;
}
__device__ __forceinline__ float sigmoidf_(float x){ return 1.f/(1.f+__expf(-x)); }

#define WAITV(N) do{ asm volatile("s_waitcnt vmcnt(" #N ")" ::: "memory"); __builtin_amdgcn_sched_barrier(0); }while(0)

__device__ __forceinline__ void gload_lds16(const void* g, void* l){
  __builtin_amdgcn_global_load_lds((const __attribute__((address_space(1))) void*)g,
                                   (__attribute__((address_space(3))) void*)l, 16, 0, 0);
}
__device__ __forceinline__ void st_dwordx2_sc(void* p, unsigned lo, unsigned hi){
  uint2 v; v.x = lo; v.y = hi;
  asm volatile("global_store_dwordx2 %0, %1, off sc0 sc1" :: "v"(p), "v"(v) : "memory");
}

// ---------------- prep: x*mask -> f32 + bf16 ----------------
__global__ __launch_bounds__(256) void k_prep(const float* __restrict__ x, const float* __restrict__ mask,
                                              float* __restrict__ xm, ushort* __restrict__ xmb){
  int i = blockIdx.x*256 + threadIdx.x;
  float4 v = ((const float4*)x)[i];
  float mk = mask[i >> 8];
  v.x*=mk; v.y*=mk; v.z*=mk; v.w*=mk;
  ((float4*)xm)[i] = v;
  ushort4 h; h.x=f2bf(v.x); h.y=f2bf(v.y); h.z=f2bf(v.z); h.w=f2bf(v.w);
  ((ushort4*)xmb)[i] = h;
}

// init h slot 0: value bf16(0), tag 1
__global__ __launch_bounds__(256) void k_hinit(unsigned* __restrict__ hw){
  hw[blockIdx.x*256 + threadIdx.x] = 1u;
}

__global__ __launch_bounds__(256) void k_cvt(const float* __restrict__ in, ushort* __restrict__ out, int n4){
  int i = blockIdx.x*256 + threadIdx.x;
  if (i < n4){
    float4 v = ((const float4*)in)[i];
    ushort4 h; h.x=f2bf(v.x); h.y=f2bf(v.y); h.z=f2bf(v.z); h.w=f2bf(v.w);
    ((ushort4*)out)[i] = h;
  }
}

// h1g *= wv[b][v] for streamed rows only (t<384); tb=3 rows are written pre-weighted by the tail GEMM
__global__ __launch_bounds__(256) void k_scale(ushort* __restrict__ h1g, const float* __restrict__ wv){
  const int i = blockIdx.x*256 + threadIdx.x;        // ushort4 idx, 0 .. 8M-1
  const int row = i >> 11;                           // token row (b*512+t)
  if ((row & 511) >= 384) return;                    // tb=3 handled in tail (weighted epilogue)
  const int b = row >> 9;
  const int v = (i >> 8) & 7;                        // col>>10
  const float s = wv[b*8 + v];
  ushort4 h = ((const ushort4*)h1g)[i];
  h.x = f2bf(bf2f(h.x)*s); h.y = f2bf(bf2f(h.y)*s);
  h.z = f2bf(bf2f(h.z)*s); h.w = f2bf(bf2f(h.w)*s);
  ((ushort4*)h1g)[i] = h;
}

// ---------------- bf16 MFMA GEMM (m97 structure) ----------------
// A-tile row base = blockIdx.x*am + aa (generalized for non-contiguous M panels)
struct EpiArgs {
  float* outf; ushort* outh;
  const float* bias; const float* wvp; const float* obias;
  int ldc; int am; int aa;
};

template<int EPI, bool INIT>
__global__ __launch_bounds__(256) void k_gemm(const ushort* __restrict__ A, const ushort* __restrict__ Bm,
                                              int lda, int ldb, int K, EpiArgs e)
{
  __shared__ ushort As[128*64];
  __shared__ ushort Bs[128*64];
  const int tid = threadIdx.x;
  const int w = tid >> 6, l = tid & 63;
  const int wr = w >> 1, wc = w & 1;
  f32x4 acc[4][4] = {};
  const size_t arow = (size_t)(blockIdx.x*e.am + e.aa);
  const size_t brow = (size_t)(blockIdx.y*128);
  const int lr = l >> 3, lcol = (l & 7) << 3;

  for (int k0 = 0; k0 < K; k0 += 64){
    __syncthreads();
    #pragma unroll
    for (int g = 0; g < 4; ++g){
      const int chunk = (g<<2) + w;
      const int row = (chunk<<3) + lr;
      gload_lds16(A + (arow + row)*lda + k0 + lcol, &As[chunk<<9]);
      gload_lds16(Bm + (brow + row)*ldb + k0 + lcol, &Bs[chunk<<9]);
    }
    __syncthreads();
    #pragma unroll
    for (int kk = 0; kk < 2; ++kk){
      bf16x8 af[4], bfr[4];
      #pragma unroll
      for (int m=0;m<4;++m) af[m]  = *(const bf16x8*)&As[(wr*64 + m*16 + (l&15))*64 + kk*32 + ((l>>4)<<3)];
      #pragma unroll
      for (int n=0;n<4;++n) bfr[n] = *(const bf16x8*)&Bs[(wc*64 + n*16 + (l&15))*64 + kk*32 + ((l>>4)<<3)];
      #pragma unroll
      for (int m=0;m<4;++m)
        #pragma unroll
        for (int n=0;n<4;++n)
          acc[m][n] = __builtin_amdgcn_mfma_f32_16x16x32_bf16(af[m], bfr[n], acc[m][n], 0, 0, 0);
    }
  }
  const int row0 = (int)arow + wr*64 + ((l>>4)<<2);
  const int col0 = blockIdx.y*128 + wc*64 + (l&15);
  #pragma unroll
  for (int m=0;m<4;++m){
    #pragma unroll
    for (int n=0;n<4;++n){
      f32x4 a = acc[m][n];
      int col = col0 + n*16;
      #pragma unroll
      for (int q=0;q<4;++q){
        int row = row0 + m*16 + q;
        float val = a[q];
        if constexpr (EPI==1){
          float xg = val + e.bias[col];
          float g = 0.5f*xg*(1.0f + erff(xg*0.70710678118f));
          e.outh[(size_t)row*e.ldc + col] = f2bf(g * e.wvp[(row>>9)*V_ + (col>>10)]);
        } else {
          size_t idx = (size_t)row*e.ldc + col;
          float prev = INIT ? e.obias[((row>>9)<<10) + col] : e.outf[idx];
          e.outf[idx] = prev + val;
        }
      }
    }
  }
}

// ================= MEGA KERNEL (R7 GRU + streamed unweighted h1 for tb 0..2) =================
// ctrl: done[768] | wm@896 | tfdone@1024..5119 | w1done@5120..5151
__global__ __launch_bounds__(256, 1) void k_mega(
    const float* __restrict__ whh, const float* __restrict__ bhh,
    const ushort* __restrict__ xmb, const ushort* __restrict__ wihb,
    const float* __restrict__ ebih, float* __restrict__ gx,
    unsigned* __restrict__ hw, const float* __restrict__ xm,
    const float* __restrict__ ttW, const float* __restrict__ ttb,
    const float* __restrict__ polW, const float* __restrict__ polb,
    ushort* __restrict__ tf, float* __restrict__ ttpol,
    const float* __restrict__ opW1, ushort* __restrict__ w1b,
    const float* __restrict__ opW2, ushort* __restrict__ w2t,
    const float* __restrict__ opb1, ushort* __restrict__ h1g,
    float* __restrict__ hsum, float* __restrict__ xsum,
    int* __restrict__ done, int* __restrict__ wm,
    int* __restrict__ tfdone, int* __restrict__ w1done, int stream)
{
  __shared__ char smem[32768];
  const int tid = threadIdx.x;
  const int w = tid >> 6, l = tid & 63;

  if (blockIdx.x < NGRU){
    // ---------------- GRU path (exact R7) ----------------
    const int c = blockIdx.x;
    const int ar = l & 15, kg = (l >> 4) << 3;
    ushort (*Hld)[264] = (ushort (*)[264])smem;
    float* Red = (float*)(smem + 4*8*264*2);

    bf16x8 Bf[3][8];
    #pragma unroll
    for (int g = 0; g < 3; ++g){
      #pragma unroll
      for (int s = 0; s < 8; ++s){
        const float* src = whh + ((size_t)((g<<10) + (c<<4) + ar))*1024 + (w<<8) + (s<<5) + kg;
        float4 u0 = *(const float4*)src;
        float4 u1 = *(const float4*)(src + 4);
        bf16x8 f;
        f[0]=(short)f2bf(u0.x); f[1]=(short)f2bf(u0.y); f[2]=(short)f2bf(u0.z); f[3]=(short)f2bf(u0.w);
        f[4]=(short)f2bf(u1.x); f[5]=(short)f2bf(u1.y); f[6]=(short)f2bf(u1.z); f[7]=(short)f2bf(u1.w);
        Bf[g][s] = f;
      }
    }
    const int pb = (w << 1) + ((l >> 4) & 1);
    const int pi = l & 15;
    const int dg = (c << 4) + pi;
    const float bhr = bhh[dg], bhz = bhh[1024 + dg], bhn = bhh[2048 + dg];
    float hp = 0.f, hacc = 0.f;
    __syncthreads();

    // gate gx block 0
    {
      const int* dp = done + l*3;
      int f0, f1, f2;
      while (true){
        asm volatile("global_load_dword %0, %1, off sc0 sc1" : "=v"(f0) : "v"(dp)   : "memory");
        asm volatile("global_load_dword %0, %1, off sc0 sc1" : "=v"(f1) : "v"(dp+1) : "memory");
        asm volatile("global_load_dword %0, %1, off sc0 sc1" : "=v"(f2) : "v"(dp+2) : "memory");
        WAITV(0);
        if (__all((f0 & f1 & f2) == 1)) break;
        __builtin_amdgcn_s_sleep(4);
      }
    }
    __syncthreads();
    float xr, xz, xn, nxr, nxz, nxn;
    if (l < 32){
      const float* g0 = gx + ((size_t)(pb*512))*TDK + dg;
      asm volatile("global_load_dword %0, %1, off sc0 sc1" : "=v"(xr) : "v"(g0)        : "memory");
      asm volatile("global_load_dword %0, %1, off sc0 sc1" : "=v"(xz) : "v"(g0 + 1024) : "memory");
      asm volatile("global_load_dword %0, %1, off sc0 sc1" : "=v"(xn) : "v"(g0 + 2048) : "memory");
    }
    WAITV(0);

    for (int t = 0; t < 512; ++t){
      if ((t & 127) == 0 && t){
        const int tq = t >> 7;
        const int* dp = done + tq*192 + l*3;
        int f0, f1, f2;
        while (true){
          asm volatile("global_load_dword %0, %1, off sc0 sc1" : "=v"(f0) : "v"(dp)   : "memory");
          asm volatile("global_load_dword %0, %1, off sc0 sc1" : "=v"(f1) : "v"(dp+1) : "memory");
          asm volatile("global_load_dword %0, %1, off sc0 sc1" : "=v"(f2) : "v"(dp+2) : "memory");
          WAITV(0);
          if (__all((f0 & f1 & f2) == 1)) break;
          __builtin_amdgcn_s_sleep(4);
        }
        __syncthreads();
        if (l < 32){
          const float* g0 = gx + ((size_t)(pb*512 + t))*TDK + dg;
          asm volatile("global_load_dword %0, %1, off sc0 sc1" : "=v"(xr) : "v"(g0)        : "memory");
          asm volatile("global_load_dword %0, %1, off sc0 sc1" : "=v"(xz) : "v"(g0 + 1024) : "memory");
          asm volatile("global_load_dword %0, %1, off sc0 sc1" : "=v"(xn) : "v"(g0 + 2048) : "memory");
        }
        WAITV(0);
      }
      uint4 rw[8];
      unsigned ok = 0;
      const unsigned tagv = (unsigned)(t + 1);
      const unsigned* qb = hw + ((size_t)t << 13) + (w << 8) + (l << 2);
      #pragma unroll
      for (int j = 0; j < 8; ++j)
        asm volatile("global_load_dwordx4 %0, %1, off sc0 sc1" : "=v"(rw[j]) : "v"(qb + (j << 10)) : "memory");
      const bool gxi = (((t+1) & 127) != 0) && (t+1 < 512);
      if (gxi && l < 32){
        const float* g0 = gx + ((size_t)(pb*512 + t + 1))*TDK + dg;
        asm volatile("global_load_dword %0, %1, off sc0 sc1" : "=v"(nxr) : "v"(g0)        : "memory");
        asm volatile("global_load_dword %0, %1, off sc0 sc1" : "=v"(nxz) : "v"(g0 + 1024) : "memory");
        asm volatile("global_load_dword %0, %1, off sc0 sc1" : "=v"(nxn) : "v"(g0 + 2048) : "memory");
      }
      if (gxi) { WAITV(3); } else { WAITV(0); }
      #pragma unroll
      for (int j = 0; j < 8; ++j){
        unsigned m = (rw[j].x ^ tagv) | (rw[j].y ^ tagv) | (rw[j].z ^ tagv) | (rw[j].w ^ tagv);
        if ((m & 0xFFFFu) == 0u) ok |= (1u << j);
      }
      while (!__all(ok == 0xFFu)){
        #pragma unroll
        for (int j = 0; j < 8; ++j){
          if (!(ok & (1u << j)))
            asm volatile("global_load_dwordx4 %0, %1, off sc0 sc1" : "=v"(rw[j]) : "v"(qb + (j << 10)) : "memory");
        }
        WAITV(0);
        #pragma unroll
        for (int j = 0; j < 8; ++j){
          if (!(ok & (1u << j))){
            unsigned m = (rw[j].x ^ tagv) | (rw[j].y ^ tagv) | (rw[j].z ^ tagv) | (rw[j].w ^ tagv);
            if ((m & 0xFFFFu) == 0u) ok |= (1u << j);
          }
        }
      }
      #pragma unroll
      for (int j = 0; j < 8; ++j){
        unsigned d0 = __builtin_amdgcn_perm(rw[j].y, rw[j].x, 0x07060302u);
        unsigned d1 = __builtin_amdgcn_perm(rw[j].w, rw[j].z, 0x07060302u);
        union { unsigned u[2]; unsigned long long ull; } cv; cv.u[0]=d0; cv.u[1]=d1;
        *(unsigned long long*)&Hld[w*8 + j][l<<2] = cv.ull;
      }
      f32x4 ac0 = {0.f,0.f,0.f,0.f}, ac1 = {0.f,0.f,0.f,0.f}, ac2 = {0.f,0.f,0.f,0.f};
      #pragma unroll
      for (int s = 0; s < 8; ++s){
        bf16x8 af = *(const bf16x8*)&Hld[w*8 + (ar & 7)][(s << 5) + kg];
        ac0 = __builtin_amdgcn_mfma_f32_16x16x32_bf16(af, Bf[0][s], ac0, 0, 0, 0);
        ac1 = __builtin_amdgcn_mfma_f32_16x16x32_bf16(af, Bf[1][s], ac1, 0, 0, 0);
        ac2 = __builtin_amdgcn_mfma_f32_16x16x32_bf16(af, Bf[2][s], ac2, 0, 0, 0);
      }
      const int cur = t & 1;
      if (l < 32){
        *(f32x4*)(&Red[cur*1536 + (w*3+0)*128 + l*4]) = ac0;
        *(f32x4*)(&Red[cur*1536 + (w*3+1)*128 + l*4]) = ac1;
        *(f32x4*)(&Red[cur*1536 + (w*3+2)*128 + l*4]) = ac2;
      }
      __syncthreads();
      if (l < 32){
        const int idx = (((pb>>2)<<4) | pi)*4 + (pb & 3);
        const float* R = Red + cur*1536;
        float ghr = R[idx]       + R[384 + idx]  + R[768 + idx]  + R[1152 + idx];
        float ghz = R[128 + idx] + R[512 + idx]  + R[896 + idx]  + R[1280 + idx];
        float ghn = R[256 + idx] + R[640 + idx]  + R[1024 + idx] + R[1408 + idx];
        float r  = sigmoidf_(xr + ghr + bhr);
        float z  = sigmoidf_(xz + ghz + bhz);
        float nn = tanhf(xn + r*(ghn + bhn));
        hp = (1.f - z)*nn + z*hp;
        hacc += hp;
        unsigned word = (((unsigned)f2bf(hp)) << 16) | (unsigned)(t + 2);
        unsigned* hdst = hw + ((size_t)(t+1) << 13) + (pb << 10) + dg;
        asm volatile("global_store_dword %0, %1, off sc0 sc1" :: "v"(hdst), "v"(word) : "memory");
      }
      if (c == 0 && tid == 0){
        asm volatile("global_store_dword %0, %1, off sc0 sc1" :: "v"(wm), "v"(t) : "memory");
      }
      if (gxi && l < 32){ xr = nxr; xz = nxz; xn = nxn; }
    }
    if (l < 32) hsum[(pb << 10) + dg] = hacc;
    return;
  }

  // ---------------- helper path ----------------
  const int hid = blockIdx.x - NGRU;            // 0..191
  ushort* As = (ushort*)smem;
  ushort* Bs = As + 8192;

  // phase 1: gx GEMM tiles in t-priority order (all 192 helpers)
  {
    const int bb = hid / 24, ni = hid % 24;
    const int wr_ = w >> 1, wc_ = w & 1;
    const int lr = l >> 3, lcol = (l & 7) << 3;
    for (int wv = 0; wv < 4; ++wv){
      const int mi = bb*4 + wv;
      f32x4 acc[4][4] = {};
      for (int k0 = 0; k0 < 1024; k0 += 64){
        __syncthreads();
        #pragma unroll
        for (int g = 0; g < 4; ++g){
          const int chunk = (g<<2) + w;
          const int row = (chunk<<3) + lr;
          gload_lds16(xmb + (size_t)(mi*128 + row)*1024 + k0 + lcol, &As[chunk<<9]);
          gload_lds16(wihb + (size_t)(ni*128 + row)*1024 + k0 + lcol, &Bs[chunk<<9]);
        }
        __syncthreads();
        #pragma unroll
        for (int kk = 0; kk < 2; ++kk){
          bf16x8 af[4], bfr[4];
          #pragma unroll
          for (int m=0;m<4;++m) af[m]  = *(const bf16x8*)&As[(wr_*64 + m*16 + (l&15))*64 + kk*32 + ((l>>4)<<3)];
          #pragma unroll
          for (int n=0;n<4;++n) bfr[n] = *(const bf16x8*)&Bs[(wc_*64 + n*16 + (l&15))*64 + kk*32 + ((l>>4)<<3)];
          #pragma unroll
          for (int m=0;m<4;++m)
            #pragma unroll
            for (int n=0;n<4;++n)
              acc[m][n] = __builtin_amdgcn_mfma_f32_16x16x32_bf16(af[m], bfr[n], acc[m][n], 0, 0, 0);
        }
      }
      const int row0 = mi*128 + wr_*64 + ((l>>4)<<2);
      const int col0 = ni*128 + wc_*64 + (l&15);
      #pragma unroll
      for (int m=0;m<4;++m){
        #pragma unroll
        for (int n=0;n<4;++n){
          f32x4 a = acc[m][n];
          int col = col0 + n*16;
          float bi = ebih[col];
          #pragma unroll
          for (int q=0;q<4;++q){
            int row = row0 + m*16 + q;
            float val = a[q] + bi;
            float* p = gx + (size_t)row*TDK + col;
            asm volatile("global_store_dword %0, %1, off sc0 sc1" :: "v"(p), "v"(val) : "memory");
          }
        }
      }
      WAITV(0);
      __syncthreads();
      if (tid == 0){
        int one = 1;
        const int* fp = done + wv*192 + hid;
        asm volatile("global_store_dword %0, %1, off sc0 sc1" :: "v"(fp), "v"(one) : "memory");
      }
      __syncthreads();
    }
  }
  // phase 2a: w1b (helpers 160..191, sc0sc1 write-through + flag)
  if (hid >= 160){
    for (int row = hid - 160; row < 8192; row += 32){
      const float* src = opW1 + (size_t)row*I_;
      ushort* dst = w1b + (size_t)row*KP_;
      for (int c0 = tid*4; c0 < KP_; c0 += 1024){
        ushort4 h;
        h.x = (c0   < I_) ? f2bf(src[c0])   : (ushort)0;
        h.y = (c0+1 < I_) ? f2bf(src[c0+1]) : (ushort)0;
        h.z = (c0+2 < I_) ? f2bf(src[c0+2]) : (ushort)0;
        h.w = (c0+3 < I_) ? f2bf(src[c0+3]) : (ushort)0;
        unsigned lo = ((unsigned)h.y << 16) | h.x;
        unsigned hi = ((unsigned)h.w << 16) | h.z;
        st_dwordx2_sc(dst + c0, lo, hi);
      }
    }
    WAITV(0);
    __syncthreads();
    if (tid == 0){
      int one = 1;
      const int* fp = w1done + (hid - 160);
      asm volatile("global_store_dword %0, %1, off sc0 sc1" :: "v"(fp), "v"(one) : "memory");
    }
  }
  // phase 2b: w2t (helpers 128..159, plain — consumed post-kernel)
  if (hid >= 128 && hid < 160){
    for (int blk = hid - 128; blk < 8192; blk += 32){
      const int v = blk >> 10, d = blk & 1023;
      const float4* src = (const float4*)(opW2 + ((size_t)(v*1024 + d))*1024);
      ushort* dst = w2t + (size_t)d*8192 + v*1024;
      float4 u = src[tid];
      ushort4 h; h.x=f2bf(u.x); h.y=f2bf(u.y); h.z=f2bf(u.z); h.w=f2bf(u.w);
      ((ushort4*)dst)[tid] = h;
    }
  }
  // phase 3: xsum
  if (hid < 32){
    const int o = hid*256 + tid;
    const int b = o >> 10, d = o & 1023;
    float s = 0.f;
    for (int t = 0; t < 512; ++t) s += xm[((size_t)(b*512 + t) << 10) + d];
    xsum[o] = s;
  }
  // phase 4+5: t-ordered interleave of tokfeat and streamed h1 tiles (h1 only tb 0..2)
  for (int tb = 0; tb < 4; ++tb){
    // --- tokfeat for t in [tb*128, tb*128+128) ---
    {
      float* xe = (float*)smem;
      for (int idx = tb*1024 + hid; idx < (tb+1)*1024; idx += NHELP){
        const int t = idx >> 3, b = idx & 7;
        const int tok = b*512 + t;
        const int need = (t+1 < 511) ? (t+1) : 511;
        if (tid == 0){
          int wmv;
          while (true){
            asm volatile("global_load_dword %0, %1, off sc0 sc1" : "=v"(wmv) : "v"(wm) : "memory");
            asm volatile("s_waitcnt vmcnt(0)" ::: "memory");
            if (wmv >= need) break;
            __builtin_amdgcn_s_sleep(64);
          }
        }
        __syncthreads();
        const unsigned tagv = (unsigned)(t + 2);
        const unsigned* src = hw + ((size_t)(t+1) << 13) + (b << 10) + (tid << 2);
        uint4 hv;
        while (true){
          asm volatile("global_load_dwordx4 %0, %1, off sc0 sc1" : "=v"(hv) : "v"(src) : "memory");
          WAITV(0);
          unsigned m = (hv.x ^ tagv) | (hv.y ^ tagv) | (hv.z ^ tagv) | (hv.w ^ tagv);
          if (__syncthreads_and((int)((m & 0xFFFFu) == 0u))) break;
          __builtin_amdgcn_s_sleep(16);
        }
        float4 xv = ((const float4*)(xm + (size_t)tok*1024))[tid];
        float4 ev;
        ev.x = bf2f((ushort)(hv.x >> 16)) + xv.x;
        ev.y = bf2f((ushort)(hv.y >> 16)) + xv.y;
        ev.z = bf2f((ushort)(hv.z >> 16)) + xv.z;
        ev.w = bf2f((ushort)(hv.w >> 16)) + xv.w;
        *(float4*)&xe[tid*4] = ev;
        ushort4 eb; eb.x=f2bf(ev.x); eb.y=f2bf(ev.y); eb.z=f2bf(ev.z); eb.w=f2bf(ev.w);
        {
          unsigned lo = ((unsigned)eb.y << 16) | eb.x;
          unsigned hi = ((unsigned)eb.w << 16) | eb.z;
          st_dwordx2_sc(&tf[(size_t)tok*KP_ + tid*4], lo, hi);
        }
        __syncthreads();
        const int j = tid >> 5, ln = tid & 31;
        const float* Wr = (j < 6) ? (ttW + j*1024) : (polW + (j-6)*1024);
        float acc = 0.f;
        for (int k = ln; k < 1024; k += 32) acc += xe[k]*Wr[k];
        #pragma unroll
        for (int m=16; m>=1; m>>=1) acc += __shfl_xor(acc, m, 32);
        if (ln == 0){
          float val = acc + ((j<6)? ttb[j] : polb[j-6]);
          ttpol[(size_t)tok*8 + j] = val;
          ushort hv2 = f2bf(val);
          asm volatile("global_store_short %0, %1, off sc0 sc1" :: "v"(&tf[(size_t)tok*KP_ + 1024 + j]), "v"((unsigned)hv2) : "memory");
        }
        if (tid < 56){
          asm volatile("global_store_short %0, %1, off sc0 sc1" :: "v"(&tf[(size_t)tok*KP_ + 1032 + tid]), "v"(0u) : "memory");
        }
        WAITV(0);
        __syncthreads();
        if (tid == 0){
          int one = 1;
          asm volatile("global_store_dword %0, %1, off sc0 sc1" :: "v"(tfdone + idx), "v"(one) : "memory");
        }
        __syncthreads();
      }
    }
    // --- streamed h1 tiles for this tb (tb 0..2 only; tb=3 runs post-kernel at full-machine rate) ---
    if (stream && tb < 3){
      const int wr_ = w >> 1, wc_ = w & 1;
      const int lr = l >> 3, lcol = (l & 7) << 3;
      for (int u2 = hid; u2 < 512; u2 += NHELP){
        const int b = u2 >> 6, n = u2 & 63;
        // gate: w1done[0..31] (tids 0..31) + tfdone for 128 tokens of (b, tb) (tids 32..159)
        {
          while (true){
            int f0 = 1;
            if (tid < 32){
              asm volatile("global_load_dword %0, %1, off sc0 sc1" : "=v"(f0) : "v"(w1done + tid) : "memory");
              asm volatile("s_waitcnt vmcnt(0)" ::: "memory");
            } else if (tid < 160){
              const int idx = (tb*128 + (tid - 32))*8 + b;
              asm volatile("global_load_dword %0, %1, off sc0 sc1" : "=v"(f0) : "v"(tfdone + idx) : "memory");
              asm volatile("s_waitcnt vmcnt(0)" ::: "memory");
            }
            if (__syncthreads_and((int)(f0 == 1))) break;
            __builtin_amdgcn_s_sleep(16);
          }
        }
        // GEMM: M=128 rows (tok b*512 + tb*128 + r), N-tile n, K=KP_
        // A/B staged via sc0sc1 register loads (L2-bypass: tf/w1b were written cross-WG in-kernel)
        const size_t arow = (size_t)(b*512 + tb*128);
        const size_t brow = (size_t)(n*128);
        f32x4 acc[4][4] = {};
        for (int k0 = 0; k0 < KP_; k0 += 64){
          __syncthreads();
          uint4 va[4], vb[4];
          #pragma unroll
          for (int g = 0; g < 4; ++g){
            const int chunk = (g<<2) + w;
            const int row = (chunk<<3) + lr;
            const ushort* pa = tf  + (arow + row)*KP_ + k0 + lcol;
            const ushort* pb = w1b + (brow + row)*KP_ + k0 + lcol;
            asm volatile("global_load_dwordx4 %0, %1, off sc0 sc1" : "=v"(va[g]) : "v"(pa) : "memory");
            asm volatile("global_load_dwordx4 %0, %1, off sc0 sc1" : "=v"(vb[g]) : "v"(pb) : "memory");
          }
          WAITV(0);
          #pragma unroll
          for (int g = 0; g < 4; ++g){
            const int chunk = (g<<2) + w;
            *(uint4*)&As[(chunk<<9) + l*8] = va[g];
            *(uint4*)&Bs[(chunk<<9) + l*8] = vb[g];
          }
          __syncthreads();
          #pragma unroll
          for (int kk = 0; kk < 2; ++kk){
            bf16x8 af[4], bfr[4];
            #pragma unroll
            for (int m=0;m<4;++m) af[m]  = *(const bf16x8*)&As[(wr_*64 + m*16 + (l&15))*64 + kk*32 + ((l>>4)<<3)];
            #pragma unroll
            for (int nn=0;nn<4;++nn) bfr[nn] = *(const bf16x8*)&Bs[(wc_*64 + nn*16 + (l&15))*64 + kk*32 + ((l>>4)<<3)];
            #pragma unroll
            for (int m=0;m<4;++m)
              #pragma unroll
              for (int nn=0;nn<4;++nn)
                acc[m][nn] = __builtin_amdgcn_mfma_f32_16x16x32_bf16(af[m], bfr[nn], acc[m][nn], 0, 0, 0);
          }
        }
        const int row0 = (int)arow + wr_*64 + ((l>>4)<<2);
        const int col0 = (int)brow + wc_*64 + (l&15);
        #pragma unroll
        for (int m=0;m<4;++m){
          #pragma unroll
          for (int nn=0;nn<4;++nn){
            f32x4 a = acc[m][nn];
            int col = col0 + nn*16;
            float bi = opb1[col];
            #pragma unroll
            for (int q=0;q<4;++q){
              int row = row0 + m*16 + q;
              float xg = a[q] + bi;
              float g = 0.5f*xg*(1.0f + erff(xg*0.70710678118f));
              h1g[(size_t)row*8192 + col] = f2bf(g);       // unweighted; plain store
            }
          }
        }
        __syncthreads();
      }
    }
  }
}

__global__ __launch_bounds__(64) void k_csum(const float* __restrict__ ttpol, float* __restrict__ csum){
  const int b = threadIdx.x >> 3, j = threadIdx.x & 7;
  float s = 0.f;
  for (int t=0; t<512; ++t) s += ttpol[((size_t)(b*512+t)<<3) + j];
  csum[threadIdx.x] = s * (1.f/512.f);
}

__global__ __launch_bounds__(256) void k_ctx(const float* __restrict__ hsum, const float* __restrict__ xsum,
                                             const float* __restrict__ csum,
                                             const float* __restrict__ c2hW, const float* __restrict__ c2hb,
                                             float* __restrict__ pgh0){
  const int i = blockIdx.x*256 + threadIdx.x;
  const int b = i >> 10, d = i & 1023;
  const float* wr = c2hW + (size_t)d*I_;
  const float* hs = hsum + (b<<10);
  const float* xs = xsum + (b<<10);
  float s = 0.f;
  for (int k=0; k<1024; ++k) s += (hs[k]+xs[k])*wr[k];
  float acc = c2hb[d] + s*(1.f/512.f);
  #pragma unroll
  for (int k=0; k<8; ++k) acc += csum[b*8+k]*wr[1024+k];
  pgh0[i] = acc;
}

__global__ __launch_bounds__(256) void k_pg(const float* __restrict__ whh, const float* __restrict__ bih,
                                            const float* __restrict__ bhh, const float* __restrict__ hin,
                                            float* __restrict__ hout){
  __shared__ float sh[8][1024];
  const int tid = threadIdx.x;
  for (int f = tid; f < 2048; f += 256) ((float4*)&sh[0][0])[f] = ((const float4*)hin)[f];
  __syncthreads();
  const int d = blockIdx.x*8 + (tid>>5), ln = tid & 31;
  const float* wr = whh + (size_t)d*1024;
  const float* wz = whh + (size_t)(1024+d)*1024;
  const float* wn = whh + (size_t)(2048+d)*1024;
  float ar[8]={0,0,0,0,0,0,0,0}, az[8]={0,0,0,0,0,0,0,0}, an[8]={0,0,0,0,0,0,0,0};
  for (int k = ln; k < 1024; k += 32){
    float r_=wr[k], z_=wz[k], n_=wn[k];
    #pragma unroll
    for (int b=0;b<8;++b){ float h = sh[b][k]; ar[b]+=h*r_; az[b]+=h*z_; an[b]+=h*n_; }
  }
  #pragma unroll
  for (int m=16; m>=1; m>>=1){
    #pragma unroll
    for (int b=0;b<8;++b){ ar[b]+=__shfl_xor(ar[b],m,32); az[b]+=__shfl_xor(az[b],m,32); an[b]+=__shfl_xor(an[b],m,32); }
  }
  if (ln == 0){
    float xr=bih[d], xz=bih[1024+d], xn=bih[2048+d];
    float br=bhh[d], bz=bhh[1024+d], bn=bhh[2048+d];
    #pragma unroll
    for (int b=0;b<8;++b){
      float r = sigmoidf_(xr + ar[b] + br);
      float z = sigmoidf_(xz + az[b] + bz);
      float nn = tanhf(xn + r*(an[b] + bn));
      hout[(b<<10)+d] = (1.f - z)*nn + z*sh[b][d];
    }
  }
}

__global__ __launch_bounds__(256) void k_wlogits(const float* __restrict__ pgh, const float* __restrict__ prjW,
                                                 const float* __restrict__ prjb, float* __restrict__ plog,
                                                 float* __restrict__ wv){
  __shared__ float lg[256];
  __shared__ float sm[256];
  const int tid = threadIdx.x;
  const int b = tid>>5, li = (tid>>3)&3, v = tid&7;
  const float* h = pgh + (size_t)(li+1)*8192 + (b<<10);
  const float* pw = prjW + (v<<10);
  float acc = prjb[v];
  for (int k=0;k<1024;++k) acc += h[k]*pw[k];
  lg[tid] = acc;
  plog[tid] = acc;
  __syncthreads();
  if (tid < 32){
    const int bb = tid>>2, ll = tid&3;
    const float* row = &lg[bb*32 + ll*8];
    float mx = row[0];
    #pragma unroll
    for (int u=1;u<8;++u) mx = fmaxf(mx, row[u]);
    float e[8], s=0.f;
    #pragma unroll
    for (int u=0;u<8;++u){ e[u]=__expf(row[u]-mx); s+=e[u]; }
    #pragma unroll
    for (int u=0;u<8;++u) sm[(bb*4+ll)*8+u] = e[u]/s;
  }
  __syncthreads();
  if (tid < 64){
    const int bb = tid>>3, u = tid&7;
    float s = sm[(bb*4+0)*8+u] + sm[(bb*4+1)*8+u] + sm[(bb*4+2)*8+u] + sm[(bb*4+3)*8+u];
    wv[bb*8+u] = 0.25f*s;
  }
}

__global__ __launch_bounds__(256) void k_obias(const float* __restrict__ wv, const float* __restrict__ opb2,
                                               float* __restrict__ obias){
  const int i = blockIdx.x*256 + threadIdx.x;
  const int b = i>>10, d = i&1023;
  float s = 0.f;
  #pragma unroll
  for (int v=0; v<8; ++v) s += wv[b*8+v]*opb2[(v<<10)+d];
  obias[i] = s;
}

__global__ __launch_bounds__(128) void k_pool2(const float* __restrict__ outb, float* __restrict__ pooled2){
  const int b = blockIdx.x >> 3;
  const int col = ((blockIdx.x & 7) << 7) + threadIdx.x;
  float mx = -3.4e38f, sm = 0.f;
  for (int t=0; t<512; ++t){
    float v = outb[((size_t)(b*512+t)<<10) + col];
    mx = fmaxf(mx, v); sm += v;
  }
  pooled2[((size_t)b<<11) + col] = mx;
  pooled2[((size_t)b<<11) + 1024 + col] = sm*(1.f/512.f);
}

__global__ __launch_bounds__(256) void k_z(const float* __restrict__ pooled2, const float* __restrict__ outW,
                                           const float* __restrict__ outBias, float* __restrict__ dout){
  __shared__ float p2[2048];
  const int o = blockIdx.x << 3;
  const int b = o >> 10, dbase = o & 1023;
  for (int f = threadIdx.x; f < 512; f += 256)
    ((float4*)p2)[f] = ((const float4*)(pooled2 + ((size_t)b<<11)))[f];
  __syncthreads();
  const int g = threadIdx.x >> 5, ln = threadIdx.x & 31;
  const int d = dbase + g;
  const float* wr = outW + ((size_t)d << 11);
  float acc = 0.f;
  for (int k = ln; k < 2048; k += 32) acc += p2[k]*wr[k];
  #pragma unroll
  for (int m=16; m>=1; m>>=1) acc += __shfl_xor(acc, m, 32);
  if (ln == 0) dout[(b<<10) + d] = acc + outBias[d];
}

__global__ __launch_bounds__(64) void k_losses(const float* __restrict__ p2g, const float* __restrict__ plog,
                                               float* __restrict__ dout){
  __shared__ float p2n[8], sq[8], pn[8];
  const int l = threadIdx.x;
  { const int b=l>>3, p=l&7; float s=0.f;
    const float* row = p2g + ((size_t)b<<11) + (p<<8);
    for (int k=0;k<256;++k){ float v=row[k]; s += v*v; }
    s += __shfl_xor(s,4,8); s += __shfl_xor(s,2,8); s += __shfl_xor(s,1,8);
    if (p==0) p2n[b] = fmaxf(sqrtf(s), 1e-12f);
  }
  if (l < 8){
    float s=0.f;
    #pragma unroll
    for (int k=0;k<32;++k){ float v=plog[l*32+k]; s+=v*v; }
    sq[l]=s; pn[l]=fmaxf(sqrtf(s),1e-12f);
  }
  __syncthreads();
  const int i=l>>3, j=l&7;
  const float* ri = p2g + ((size_t)i<<11);
  const float* rj = p2g + ((size_t)j<<11);
  float dot=0.f; for (int k=0;k<2048;++k) dot += ri[k]*rj[k];
  float sim = dot/(p2n[i]*p2n[j]);
  float pd=0.f;
  #pragma unroll
  for (int k=0;k<32;++k) pd += plog[i*32+k]*plog[j*32+k];
  float d2 = fmaxf(sq[i]+sq[j]-2.f*pd, 0.f);
  float dist = (d2>0.f)? sqrtf(d2) : 0.f;
  float psim = pd/(pn[i]*pn[j]);
  float pos = (sim>0.7f)?1.f:0.f, neg = (sim<0.7f)?1.f:0.f;
  float rs = sim*dist, ps=(1.f-psim)*pos, ns=fmaxf(psim-0.5f,0.f)*neg, pc=pos, nc=neg;
  #pragma unroll
  for (int m=32; m>=1; m>>=1){
    rs+=__shfl_xor(rs,m); ps+=__shfl_xor(ps,m); ns+=__shfl_xor(ns,m);
    pc+=__shfl_xor(pc,m); nc+=__shfl_xor(nc,m);
  }
  if (l==0){ dout[8192]=rs*(1.f/64.f); dout[8193]=(ps+ns)/(pc+nc+1e-6f); }
}

// ============================ host ============================
extern "C" void kernel_launch(void* const* d_in, const int* in_sizes, int n_in,
                              void* d_out, int out_size, void* d_ws, size_t ws_size,
                              hipStream_t stream) {
  (void)in_sizes; (void)n_in; (void)out_size;
  const float* x     = (const float*)d_in[0];
  const float* amask = (const float*)d_in[1];
  const float* eWih  = (const float*)d_in[2];
  const float* eWhh  = (const float*)d_in[3];
  const float* ebih  = (const float*)d_in[4];
  const float* ebhh  = (const float*)d_in[5];
  const float* ttW   = (const float*)d_in[6];
  const float* ttb   = (const float*)d_in[7];
  const float* polW  = (const float*)d_in[8];
  const float* polb  = (const float*)d_in[9];
  const float* c2hW  = (const float*)d_in[10];
  const float* c2hb  = (const float*)d_in[11];
  const float* pgWhh = (const float*)d_in[13];
  const float* pgbih = (const float*)d_in[14];
  const float* pgbhh = (const float*)d_in[15];
  const float* prjW  = (const float*)d_in[16];
  const float* prjb  = (const float*)d_in[17];
  const float* opW1  = (const float*)d_in[18];
  const float* opb1  = (const float*)d_in[19];
  const float* opW2  = (const float*)d_in[20];
  const float* opb2  = (const float*)d_in[21];
  const float* outW  = (const float*)d_in[22];
  const float* outB  = (const float*)d_in[23];
  float* dout = (float*)d_out;

  char* ws = (char*)d_ws;
  size_t off = 0;
  auto alloc = [&](size_t bytes)->void*{ void* p = ws + off; off += (bytes + 255) & ~(size_t)255; return p; };
  char*     R       = (char*)   alloc(64ULL*1024*1024);   // xm(16M)+gx(48M)
  float*    xm      = (float*)  R;
  float*    gx      = (float*) (R + 16ULL*1024*1024);
  ushort*   xmb     = (ushort*)  alloc(4096ULL*1024*2);
  ushort*   wihb    = (ushort*)  alloc(3072ULL*1024*2);
  unsigned* hw      = (unsigned*)alloc(513ULL*8192*4);
  float*    ttpol   = (float*)   alloc(4096ULL*8*4);
  ushort*   tf      = (ushort*)  alloc(4096ULL*KP_*2);
  ushort*   w1b     = (ushort*)  alloc(8ULL*1024*KP_*2);
  ushort*   w2t     = (ushort*)  alloc(1024ULL*8192*2);
  float*    outbuf  = (float*)   alloc(4096ULL*1024*4);
  float*    hsum    = (float*)   alloc(8192*4);
  float*    xsum    = (float*)   alloc(8192*4);
  float*    csum    = (float*)   alloc(64*4);
  float*    pgh     = (float*)   alloc(5ULL*8192*4);
  float*    plog    = (float*)   alloc(256*4);
  float*    wv      = (float*)   alloc(64*4);
  float*    obias   = (float*)   alloc(8192*4);
  float*    pooled2 = (float*)   alloc(16384*4);
  int*      ctrl    = (int*)     alloc(32768);
  int*      done    = ctrl;                     // [768]
  int*      wm      = ctrl + 896;
  int*      tfdone  = ctrl + 1024;              // [4096]
  int*      w1done  = ctrl + 5120;              // [32]
  // streamed-h1 buffer (64 MB) if workspace allows; else fall back to R-aliased weighted path
  const int do_stream = (ws_size >= off + 64ULL*1024*1024 + (1<<20)) ? 1 : 0;
  ushort*   h1g     = do_stream ? (ushort*)alloc(4096ULL*8192*2) : (ushort*)R;

  // control init + exchange-buffer init
  hipMemsetAsync(ctrl, 0, 5152*4, stream);      // done+tfdone+w1done
  hipMemsetAsync(wm, 0xFF, 4, stream);          // wm = -1
  k_hinit<<<32, 256, 0, stream>>>(hw);          // slot 0: value 0, tag 1
  k_prep<<<4096, 256, 0, stream>>>(x, amask, xm, xmb);
  k_cvt<<<3072, 256, 0, stream>>>(eWih, wihb, 3072*1024/4);

  // MEGA: recurrence + gx GEMM + w1b/w2t conversion + xsum + tokfeat + streamed h1 (tb 0..2)
  k_mega<<<256, 256, 0, stream>>>(eWhh, ebhh, xmb, wihb, ebih, gx, hw, xm,
                                  ttW, ttb, polW, polb, tf, ttpol,
                                  opW1, w1b, opW2, w2t, opb1, h1g,
                                  hsum, xsum, done, wm, tfdone, w1done, do_stream);

  // reductions + program generator
  k_csum<<<1, 64, 0, stream>>>(ttpol, csum);
  k_ctx<<<32, 256, 0, stream>>>(hsum, xsum, csum, c2hW, c2hb, pgh);
  for (int t = 0; t < 4; ++t)
    k_pg<<<128, 256, 0, stream>>>(pgWhh, pgbih, pgbhh, pgh + (size_t)t*8192, pgh + (size_t)(t+1)*8192);
  k_wlogits<<<1, 256, 0, stream>>>(pgh, prjW, prjb, plog, wv);
  k_obias<<<32, 256, 0, stream>>>(wv, opb2, obias);

  if (do_stream){
    // streamed rows (t<384): apply wv; tb=3 rows: weighted h1 GEMM at full-machine rate
    k_scale<<<32768, 256, 0, stream>>>(h1g, wv);
    EpiArgs e1{}; e1.outh = h1g; e1.bias = opb1; e1.wvp = wv; e1.ldc = 8192; e1.am = 512; e1.aa = 384;
    k_gemm<1,false><<<dim3(8,64), 256, 0, stream>>>(tf, w1b, KP_, KP_, KP_, e1);
  } else {
    // fallback: full weighted h1 in tail (h1g aliases R; xm/gx dead by now)
    EpiArgs e1{}; e1.outh = h1g; e1.bias = opb1; e1.wvp = wv; e1.ldc = 8192; e1.am = 128; e1.aa = 0;
    k_gemm<1,false><<<dim3(32,64), 256, 0, stream>>>(tf, w1b, KP_, KP_, KP_, e1);
  }
  { EpiArgs e2{}; e2.outf = outbuf; e2.obias = obias; e2.ldc = 1024; e2.am = 128; e2.aa = 0;
    k_gemm<2,true><<<dim3(32,8), 256, 0, stream>>>(h1g, w2t, 8192, 8192, 8192, e2); }

  // pooling + z + losses
  k_pool2<<<64, 128, 0, stream>>>(outbuf, pooled2);
  k_z<<<1024, 256, 0, stream>>>(pooled2, outW, outB, dout);
  k_losses<<<1, 64, 0, stream>>>(pooled2, plog, dout);
}